// Round 12
// baseline (141.885 us; speedup 1.0000x reference)
//
#include <hip/hip_runtime.h>

#define NPTS 16384
#define KN   16
#define CIN  64
#define COUT 64
#define KSIZ 16
#define PTS  16
#define ITERS 4

typedef _Float16 h4v    __attribute__((ext_vector_type(4)));
typedef _Float16 h8v    __attribute__((ext_vector_type(8)));
typedef __fp16   fp16x2 __attribute__((ext_vector_type(2)));
typedef float    f32x4  __attribute__((ext_vector_type(4)));

union H2U { fp16x2 h; unsigned u; };
union H4U { h4v v; fp16x2 p[2]; uint2 u2; };
union H8U { h8v v; uint4 u4; };

// ws layout: [0,256) folded layer-1 (64 packed-f16 dwords); [512, 512+131072) wf;
// [131584, +8388608) f16 feature table (only if ws_size allows).
#define WS_WF_OFF   512
#define WS_F16_OFF  131584
#define WS_NEEDED   (131584ull + 8388608ull)

// prep: blocks 0..31 pack W*(1/16) into f16 B-fragment order (4 tiles per block);
// block 32 folds layer-1; blocks 33.. convert features fp32 -> f16 (RNE).
__global__ void prep_kernel(const float* __restrict__ weight,
                            const float* __restrict__ w1,
                            const float* __restrict__ b1,
                            const float* __restrict__ centers,
                            const float* __restrict__ features,
                            unsigned* __restrict__ wsp,
                            uint4* __restrict__ wf,
                            uint4* __restrict__ fb16) {
    const int b = blockIdx.x;
    const int t = threadIdx.x;
    if (b < 32) {
        // slot s (0..1023) <-> (j,c): j = s>>6, c = s&63 (byte 2s in [j][c] f16 row).
        // Fragment: K-step kk, n-tile nt, lane l, elem e -> s = kk*32 + (l>>4)*8 + e,
        // o = nt*16 + (l&15). Consumer uses identical maps -> k-perm-invariant.
        const int bp = b*4 + (t>>6);
        const int kk = bp >> 2, nt = bp & 3;
        const int l = t & 63, li = l & 15, g = l >> 4;
        unsigned short u[8];
        #pragma unroll
        for (int e = 0; e < 8; ++e) {
            int s = kk*32 + g*8 + e;
            int j = s >> 6;
            int c = s & 63;
            union { _Float16 h; unsigned short s16; } cv;
            cv.h = (_Float16)(weight[(c*16 + j)*64 + nt*16 + li] * 0.0625f);
            u[e] = cv.s16;
        }
        uint4 v;
        v.x = u[0] | ((unsigned)u[1] << 16);
        v.y = u[2] | ((unsigned)u[3] << 16);
        v.z = u[4] | ((unsigned)u[5] << 16);
        v.w = u[6] | ((unsigned)u[7] << 16);
        wf[(kk*4 + nt)*64 + l] = v;
    } else if (b == 32) {
        __shared__ float tmp[4][32];
        if (t < 32) {
            int n = t;
            float s0 = 0.f, s1 = 0.f, s2 = 0.f, bf = b1[n];
            for (int s = 0; s < KSIZ; ++s) {
                float a0 = w1[(0*KSIZ + s)*32 + n];
                float a1 = w1[(1*KSIZ + s)*32 + n];
                float a2 = w1[(2*KSIZ + s)*32 + n];
                s0 += a0; s1 += a1; s2 += a2;
                bf -= centers[0*KSIZ+s]*a0 + centers[1*KSIZ+s]*a1 + centers[2*KSIZ+s]*a2;
            }
            tmp[0][n] = s0; tmp[1][n] = s1; tmp[2][n] = s2; tmp[3][n] = bf;
        }
        __syncthreads();
        if (t < 64) {
            const int row = t >> 4, q = t & 15;
            union { _Float16 h[2]; unsigned u; } pk;
            pk.h[0] = (_Float16)tmp[row][2*q];
            pk.h[1] = (_Float16)tmp[row][2*q+1];
            wsp[row*16 + q] = pk.u;
        }
    } else {
        const size_t e0 = ((size_t)(b - 33)*256 + t) * 8;
        const float4 f0 = *(const float4*)(features + e0);
        const float4 f1 = *(const float4*)(features + e0 + 4);
        union { _Float16 h[8]; uint4 v; } o;
        o.h[0] = (_Float16)f0.x; o.h[1] = (_Float16)f0.y;
        o.h[2] = (_Float16)f0.z; o.h[3] = (_Float16)f0.w;
        o.h[4] = (_Float16)f1.x; o.h[5] = (_Float16)f1.y;
        o.h[6] = (_Float16)f1.z; o.h[7] = (_Float16)f1.w;
        fb16[e0 >> 3] = o.v;
    }
}

// Pipelined persistent kernel: each block runs ITERS=4 consecutive 16-pt tiles.
__global__ __launch_bounds__(256, 4)
void ptconv_pipe(const float* __restrict__ input_pts,
                 const float* __restrict__ output_pts,
                 const float* __restrict__ bias,
                 const float* __restrict__ w2,
                 const float* __restrict__ b2,
                 const float* __restrict__ w3,
                 const float* __restrict__ b3,
                 const int*   __restrict__ indices,
                 const unsigned* __restrict__ folded,
                 const uint4* __restrict__ wf,
                 const uint2* __restrict__ fb16,
                 float* __restrict__ out) {
    // LDS 32768: s_agg[16 pts][2048B] rows [j][c] f16, XOR-swizzled by ((pt&7)<<4)
    // on both store and read. Wave w's quarter also holds its own h1 rows (l*80B)
    // during layers 1-3 (wave-private alias).
    __shared__ __align__(16) char smem[32768];
    char* s_agg = smem;

    const int t    = threadIdx.x;
    const int l    = t & 63;
    const int wave = t >> 6;
    const int li   = l & 15;
    const int g    = l >> 4;
    const int base_m0 = blockIdx.x * (PTS*ITERS);   // 64 consecutive points
    const int bbk   = base_m0 >> 14;                // whole block one batch
    const int mloc  = base_m0 & (NPTS-1);
    const int p1 = t >> 4, k1 = t & 15;

    const int*   idxB  = indices    + (size_t)bbk*NPTS*KN;
    const float* ptsB  = input_pts  + (size_t)bbk*NPTS*3;
    const float* optsB = output_pts + (size_t)bbk*NPTS*3;
    const uint2* fb16B = fb16 + (size_t)bbk*NPTS*(CIN/4);

    // iteration-invariant fragments / biases
    h8v w2f; h4v w3f;
    #pragma unroll
    for (int e = 0; e < 8; ++e) w2f[e] = (_Float16)w2[(8*g+e)*16 + li];
    #pragma unroll
    for (int e = 0; e < 4; ++e) w3f[e] = (_Float16)w3[(4*g+e)*16 + li];
    const f32x4 b2v4  = *(const f32x4*)(b2 + 4*g);
    const float b3v   = b3[li];
    const float biasO = bias[wave*16 + li];
    const uint4* wp   = wf + wave*64 + l;

    // ---- prologue: tile-0 cold chain ----
    float cip0, cip1, cip2, cop0, cop1, cop2;
    H4U gA0, gA1, gA2, gA3, gB0, gB1, gB2, gB3;
    H4U gC0, gC1, gC2, gC3, gD0, gD1, gD2, gD3;
    {
        const int nn = mloc + p1;
        const int idxv = idxB[nn*KN + k1];
        cop0 = optsB[nn*3+0]; cop1 = optsB[nn*3+1]; cop2 = optsB[nn*3+2];
        cip0 = ptsB[(size_t)idxv*3+0];
        cip1 = ptsB[(size_t)idxv*3+1];
        cip2 = ptsB[(size_t)idxv*3+2];
        const int4 iA = *(const int4*)(idxB + (mloc + wave*4+0)*KN + 4*g);
        const int4 iB = *(const int4*)(idxB + (mloc + wave*4+1)*KN + 4*g);
        const int4 iC = *(const int4*)(idxB + (mloc + wave*4+2)*KN + 4*g);
        const int4 iD = *(const int4*)(idxB + (mloc + wave*4+3)*KN + 4*g);
        gA0.u2 = fb16B[(size_t)iA.x*16 + li]; gA1.u2 = fb16B[(size_t)iA.y*16 + li];
        gA2.u2 = fb16B[(size_t)iA.z*16 + li]; gA3.u2 = fb16B[(size_t)iA.w*16 + li];
        gB0.u2 = fb16B[(size_t)iB.x*16 + li]; gB1.u2 = fb16B[(size_t)iB.y*16 + li];
        gB2.u2 = fb16B[(size_t)iB.z*16 + li]; gB3.u2 = fb16B[(size_t)iB.w*16 + li];
        gC0.u2 = fb16B[(size_t)iC.x*16 + li]; gC1.u2 = fb16B[(size_t)iC.y*16 + li];
        gC2.u2 = fb16B[(size_t)iC.z*16 + li]; gC3.u2 = fb16B[(size_t)iC.w*16 + li];
        gD0.u2 = fb16B[(size_t)iD.x*16 + li]; gD1.u2 = fb16B[(size_t)iD.y*16 + li];
        gD2.u2 = fb16B[(size_t)iD.z*16 + li]; gD3.u2 = fb16B[(size_t)iD.w*16 + li];
    }

    #pragma unroll 1
    for (int it = 0; it < ITERS; ++it) {
        const int m0i   = base_m0 + it*PTS;
        const bool pf   = (it + 1 < ITERS);
        const int mlocN = mloc + (it+1)*PTS;

        // ---- step 1: prefetch next tile's idx + op (independent loads) ----
        int idxvN = 0;
        float opN0 = 0.f, opN1 = 0.f, opN2 = 0.f;
        int4 iA, iB, iC, iD;
        if (pf) {
            const int nnN = mlocN + p1;
            idxvN = idxB[nnN*KN + k1];
            opN0 = optsB[nnN*3+0]; opN1 = optsB[nnN*3+1]; opN2 = optsB[nnN*3+2];
            iA = *(const int4*)(idxB + (mlocN + wave*4+0)*KN + 4*g);
            iB = *(const int4*)(idxB + (mlocN + wave*4+1)*KN + 4*g);
            iC = *(const int4*)(idxB + (mlocN + wave*4+2)*KN + 4*g);
            iD = *(const int4*)(idxB + (mlocN + wave*4+3)*KN + 4*g);
        }

        // ---- layer 1: packed f16 (uniform params -> scalar loads) ----
        {
            const __fp16 r0h = (__fp16)(cip0-cop0);
            const __fp16 r1h = (__fp16)(cip1-cop1);
            const __fp16 r2h = (__fp16)(cip2-cop2);
            fp16x2 r0p = {r0h, r0h}, r1p = {r1h, r1h}, r2p = {r2h, r2h};
            const fp16x2 zz = {(__fp16)0.f, (__fp16)0.f};
            uint4* dst = (uint4*)(smem + wave*8192 + l*80);
            unsigned o8[8];
            #pragma unroll
            for (int half = 0; half < 2; ++half) {
                #pragma unroll
                for (int qq = 0; qq < 8; ++qq) {
                    const int q = half*8 + qq;
                    H2U a, u0, u1, u2;
                    a.u  = folded[48+q];
                    u0.u = folded[q];
                    u1.u = folded[16+q];
                    u2.u = folded[32+q];
                    fp16x2 acc = r0p*u0.h + a.h;
                    acc = r1p*u1.h + acc;
                    acc = r2p*u2.h + acc;
                    acc = __builtin_elementwise_max(acc, zz);
                    H2U o; o.h = acc; o8[qq] = o.u;
                }
                dst[half*2+0] = make_uint4(o8[0], o8[1], o8[2], o8[3]);
                dst[half*2+1] = make_uint4(o8[4], o8[5], o8[6], o8[7]);
            }
        }

        // ---- layers 2+3 on MFMA, register-chained ----
        h4v dreg0, dreg1, dreg2, dreg3;
#define L23(PP, DREG) { \
        h8v B2 = *(const h8v*)(smem + wave*8192 + ((PP)*16 + li)*80 + g*16); \
        f32x4 a2 = b2v4; \
        a2 = __builtin_amdgcn_mfma_f32_16x16x32_f16(w2f, B2, a2, 0, 0, 0); \
        H4U A3; \
        A3.p[0] = __builtin_amdgcn_cvt_pkrtz(fmaxf(a2[0],0.f), fmaxf(a2[1],0.f)); \
        A3.p[1] = __builtin_amdgcn_cvt_pkrtz(fmaxf(a2[2],0.f), fmaxf(a2[3],0.f)); \
        f32x4 a3 = {b3v, b3v, b3v, b3v}; \
        a3 = __builtin_amdgcn_mfma_f32_16x16x16f16(A3.v, w3f, a3, 0, 0, 0); \
        H4U Dv; \
        Dv.p[0] = __builtin_amdgcn_cvt_pkrtz(fmaxf(a3[0],0.f), fmaxf(a3[1],0.f)); \
        Dv.p[1] = __builtin_amdgcn_cvt_pkrtz(fmaxf(a3[2],0.f), fmaxf(a3[3],0.f)); \
        DREG = Dv.v; }
        L23(0, dreg0) L23(1, dreg1) L23(2, dreg2) L23(3, dreg3)
#undef L23

        // ---- phase 2 (consumes gA..gD); swizzled agg store ----
#define P2STORE(PP, E0,E1,E2,E3) { \
        const int pix_ = wave*4 + (PP); \
        const unsigned swz_ = (unsigned)((pix_ & 7) << 4); \
        char* ab_ = s_agg + pix_*2048; \
        _Pragma("unroll") \
        for (int r = 0; r < 4; ++r) { \
            H2U d01, d23; \
            d01.h = __builtin_amdgcn_cvt_pkrtz(E0[r], E1[r]); \
            d23.h = __builtin_amdgcn_cvt_pkrtz(E2[r], E3[r]); \
            *(uint2*)(ab_ + ((unsigned)((4*g + r)*128 + 8*li) ^ swz_)) = \
                make_uint2(d01.u, d23.u); \
        } }
#define P2F16(PP, R0,R1,R2,R3) { \
        f32x4 z = {0.f,0.f,0.f,0.f}; \
        f32x4 e0_, e1_, e2_, e3_; \
        { H4U B_; B_.v = (h4v){R0.v[0], R1.v[0], R2.v[0], R3.v[0]}; \
          e0_ = __builtin_amdgcn_mfma_f32_16x16x16f16(dreg##PP, B_.v, z, 0, 0, 0); } \
        { H4U B_; B_.v = (h4v){R0.v[1], R1.v[1], R2.v[1], R3.v[1]}; \
          e1_ = __builtin_amdgcn_mfma_f32_16x16x16f16(dreg##PP, B_.v, z, 0, 0, 0); } \
        { H4U B_; B_.v = (h4v){R0.v[2], R1.v[2], R2.v[2], R3.v[2]}; \
          e2_ = __builtin_amdgcn_mfma_f32_16x16x16f16(dreg##PP, B_.v, z, 0, 0, 0); } \
        { H4U B_; B_.v = (h4v){R0.v[3], R1.v[3], R2.v[3], R3.v[3]}; \
          e3_ = __builtin_amdgcn_mfma_f32_16x16x16f16(dreg##PP, B_.v, z, 0, 0, 0); } \
        P2STORE(PP, e0_, e1_, e2_, e3_) }
        P2F16(0, gA0, gA1, gA2, gA3)
        P2F16(1, gB0, gB1, gB2, gB3)
        P2F16(2, gC0, gC1, gC2, gC3)
        P2F16(3, gD0, gD1, gD2, gD3)
#undef P2F16
#undef P2STORE

        // ---- step 5: next tile's ip gather (idxvN arrived by now) + wf preload ----
        float ipN0 = 0.f, ipN1 = 0.f, ipN2 = 0.f;
        if (pf) {
            ipN0 = ptsB[(size_t)idxvN*3+0];
            ipN1 = ptsB[(size_t)idxvN*3+1];
            ipN2 = ptsB[(size_t)idxvN*3+2];
        }
        uint4 q0 = wp[0*256], q1 = wp[1*256], q2 = wp[2*256], q3 = wp[3*256];
        uint4 q4 = wp[4*256], q5 = wp[5*256], q6 = wp[6*256], q7 = wp[7*256];

        // barrier H: LDS drained, globals NOT drained (wf + ipN stay in flight)
        asm volatile("s_waitcnt lgkmcnt(0)" ::: "memory");
        __builtin_amdgcn_s_barrier();
        asm volatile("" ::: "memory");

        // ---- phase 3: 4 independent accumulators, 8-deep rolling wf window ----
        __builtin_amdgcn_s_setprio(1);
        f32x4 a0 = {0.f,0.f,0.f,0.f}, a1 = a0, a2 = a0, a3 = a0;
        const unsigned swr = (unsigned)((li & 7) << 4);
#define AREAD(KK) (*(const h8v*)(s_agg + li*2048 + (((KK)*64 + g*16) ^ swr)))
#define MFS(KK, Q, ACC)  { H8U bu_; bu_.u4 = Q; \
        ACC = __builtin_amdgcn_mfma_f32_16x16x32_f16(AREAD(KK), bu_.v, ACC, 0, 0, 0); }
#define MFSL(KK, Q, ACC) MFS(KK, Q, ACC) Q = wp[((KK)+8)*256];
        MFSL(0, q0, a0) MFSL(1, q1, a1) MFSL(2, q2, a2) MFSL(3, q3, a3)
        MFSL(4, q4, a0) MFSL(5, q5, a1) MFSL(6, q6, a2) MFSL(7, q7, a3)
        MFSL(8, q0, a0) MFSL(9, q1, a1) MFSL(10, q2, a2) MFSL(11, q3, a3)
        MFSL(12, q4, a0) MFSL(13, q5, a1) MFSL(14, q6, a2) MFSL(15, q7, a3)
        MFSL(16, q0, a0) MFSL(17, q1, a1) MFSL(18, q2, a2) MFSL(19, q3, a3)
        MFSL(20, q4, a0) MFSL(21, q5, a1) MFSL(22, q6, a2) MFSL(23, q7, a3)
        MFS(24, q0, a0) MFS(25, q1, a1) MFS(26, q2, a2) MFS(27, q3, a3)
        MFS(28, q4, a0) MFS(29, q5, a1) MFS(30, q6, a2) MFS(31, q7, a3)
#undef MFSL
#undef MFS
#undef AREAD
        __builtin_amdgcn_s_setprio(0);

        const f32x4 acc = (a0 + a1) + (a2 + a3);
        #pragma unroll
        for (int r = 0; r < 4; ++r) {
            const int mr = g*4 + r;
            out[(size_t)(m0i + mr)*COUT + wave*16 + li] = acc[r] + biasO;
        }

        // barrier I: all phase-3 LDS reads done before next iter's h1/agg writes
        asm volatile("" ::: "memory");
        __builtin_amdgcn_s_barrier();
        asm volatile("" ::: "memory");

        // ---- step 9: next tile's feature gathers into freed gA..gD ----
        if (pf) {
            gA0.u2 = fb16B[(size_t)iA.x*16 + li]; gA1.u2 = fb16B[(size_t)iA.y*16 + li];
            gA2.u2 = fb16B[(size_t)iA.z*16 + li]; gA3.u2 = fb16B[(size_t)iA.w*16 + li];
            gB0.u2 = fb16B[(size_t)iB.x*16 + li]; gB1.u2 = fb16B[(size_t)iB.y*16 + li];
            gB2.u2 = fb16B[(size_t)iB.z*16 + li]; gB3.u2 = fb16B[(size_t)iB.w*16 + li];
            gC0.u2 = fb16B[(size_t)iC.x*16 + li]; gC1.u2 = fb16B[(size_t)iC.y*16 + li];
            gC2.u2 = fb16B[(size_t)iC.z*16 + li]; gC3.u2 = fb16B[(size_t)iC.w*16 + li];
            gD0.u2 = fb16B[(size_t)iD.x*16 + li]; gD1.u2 = fb16B[(size_t)iD.y*16 + li];
            gD2.u2 = fb16B[(size_t)iD.z*16 + li]; gD3.u2 = fb16B[(size_t)iD.w*16 + li];
            asm volatile("" ::: "memory");   // pin issue point
            cip0 = ipN0; cip1 = ipN1; cip2 = ipN2;
            cop0 = opN0; cop1 = opN1; cop2 = opN2;
        }
    }
}

// Fallback (ws too small for f16 table): R11-style single-tile, fp32 gathers.
__global__ __launch_bounds__(256, 4)
void ptconv_f32(const float* __restrict__ features,
                const float* __restrict__ input_pts,
                const float* __restrict__ output_pts,
                const float* __restrict__ bias,
                const float* __restrict__ w2,
                const float* __restrict__ b2,
                const float* __restrict__ w3,
                const float* __restrict__ b3,
                const int*   __restrict__ indices,
                const unsigned* __restrict__ folded,
                const uint4* __restrict__ wf,
                float* __restrict__ out) {
    __shared__ __align__(16) char smem[32768];
    char* s_agg = smem;
    const int t = threadIdx.x, l = t & 63, wave = t >> 6, li = l & 15, g = l >> 4;
    const int m0 = blockIdx.x * PTS, bbk = m0 >> 14, mloc = m0 & (NPTS-1);
    const int*   idxB  = indices    + (size_t)bbk*NPTS*KN;
    const float* ptsB  = input_pts  + (size_t)bbk*NPTS*3;
    const float* optsB = output_pts + (size_t)bbk*NPTS*3;
    const float* fb    = features   + (size_t)bbk*NPTS*CIN;
    const int p1 = t >> 4, k1 = t & 15;
    const int nn = mloc + p1;
    const int idxv = idxB[nn*KN + k1];
    const float cop0 = optsB[nn*3+0], cop1 = optsB[nn*3+1], cop2 = optsB[nn*3+2];
    const float cip0 = ptsB[(size_t)idxv*3+0];
    const float cip1 = ptsB[(size_t)idxv*3+1];
    const float cip2 = ptsB[(size_t)idxv*3+2];
    const int4 idA = *(const int4*)(idxB + (mloc + wave*4+0)*KN + 4*g);
    const int4 idB = *(const int4*)(idxB + (mloc + wave*4+1)*KN + 4*g);
    const int4 idC = *(const int4*)(idxB + (mloc + wave*4+2)*KN + 4*g);
    const int4 idD = *(const int4*)(idxB + (mloc + wave*4+3)*KN + 4*g);
    f32x4 fA0 = *(const f32x4*)(fb + (size_t)idA.x*CIN + 4*li);
    f32x4 fA1 = *(const f32x4*)(fb + (size_t)idA.y*CIN + 4*li);
    f32x4 fA2 = *(const f32x4*)(fb + (size_t)idA.z*CIN + 4*li);
    f32x4 fA3 = *(const f32x4*)(fb + (size_t)idA.w*CIN + 4*li);
    f32x4 fB0 = *(const f32x4*)(fb + (size_t)idB.x*CIN + 4*li);
    f32x4 fB1 = *(const f32x4*)(fb + (size_t)idB.y*CIN + 4*li);
    f32x4 fB2 = *(const f32x4*)(fb + (size_t)idB.z*CIN + 4*li);
    f32x4 fB3 = *(const f32x4*)(fb + (size_t)idB.w*CIN + 4*li);
    h8v w2f; h4v w3f;
    #pragma unroll
    for (int e = 0; e < 8; ++e) w2f[e] = (_Float16)w2[(8*g+e)*16 + li];
    #pragma unroll
    for (int e = 0; e < 4; ++e) w3f[e] = (_Float16)w3[(4*g+e)*16 + li];
    const f32x4 b2v4 = *(const f32x4*)(b2 + 4*g);
    const float b3v = b3[li], biasO = bias[wave*16 + li];
    const uint4* wp = wf + wave*64 + l;
    {
        const __fp16 r0h = (__fp16)(cip0-cop0), r1h = (__fp16)(cip1-cop1), r2h = (__fp16)(cip2-cop2);
        fp16x2 r0p = {r0h, r0h}, r1p = {r1h, r1h}, r2p = {r2h, r2h};
        const fp16x2 zz = {(__fp16)0.f, (__fp16)0.f};
        uint4* dst = (uint4*)(smem + wave*8192 + l*80);
        unsigned o8[8];
        #pragma unroll
        for (int half = 0; half < 2; ++half) {
            #pragma unroll
            for (int qq = 0; qq < 8; ++qq) {
                const int q = half*8 + qq;
                H2U a, u0, u1, u2;
                a.u = folded[48+q]; u0.u = folded[q]; u1.u = folded[16+q]; u2.u = folded[32+q];
                fp16x2 acc = r0p*u0.h + a.h;
                acc = r1p*u1.h + acc;
                acc = r2p*u2.h + acc;
                acc = __builtin_elementwise_max(acc, zz);
                H2U o; o.h = acc; o8[qq] = o.u;
            }
            dst[half*2+0] = make_uint4(o8[0], o8[1], o8[2], o8[3]);
            dst[half*2+1] = make_uint4(o8[4], o8[5], o8[6], o8[7]);
        }
    }
    h4v dreg0, dreg1, dreg2, dreg3;
#define L23(PP, DREG) { \
    h8v B2 = *(const h8v*)(smem + wave*8192 + ((PP)*16 + li)*80 + g*16); \
    f32x4 a2 = b2v4; \
    a2 = __builtin_amdgcn_mfma_f32_16x16x32_f16(w2f, B2, a2, 0, 0, 0); \
    H4U A3; \
    A3.p[0] = __builtin_amdgcn_cvt_pkrtz(fmaxf(a2[0],0.f), fmaxf(a2[1],0.f)); \
    A3.p[1] = __builtin_amdgcn_cvt_pkrtz(fmaxf(a2[2],0.f), fmaxf(a2[3],0.f)); \
    f32x4 a3 = {b3v, b3v, b3v, b3v}; \
    a3 = __builtin_amdgcn_mfma_f32_16x16x16f16(A3.v, w3f, a3, 0, 0, 0); \
    H4U Dv; \
    Dv.p[0] = __builtin_amdgcn_cvt_pkrtz(fmaxf(a3[0],0.f), fmaxf(a3[1],0.f)); \
    Dv.p[1] = __builtin_amdgcn_cvt_pkrtz(fmaxf(a3[2],0.f), fmaxf(a3[3],0.f)); \
    DREG = Dv.v; }
    L23(0, dreg0) L23(1, dreg1) L23(2, dreg2) L23(3, dreg3)
#undef L23
#define P2STORE(PP, E0,E1,E2,E3) { \
    const int pix_ = wave*4 + (PP); \
    const unsigned swz_ = (unsigned)((pix_ & 7) << 4); \
    char* ab_ = s_agg + pix_*2048; \
    _Pragma("unroll") \
    for (int r = 0; r < 4; ++r) { \
        H2U d01, d23; \
        d01.h = __builtin_amdgcn_cvt_pkrtz(E0[r], E1[r]); \
        d23.h = __builtin_amdgcn_cvt_pkrtz(E2[r], E3[r]); \
        *(uint2*)(ab_ + ((unsigned)((4*g + r)*128 + 8*li) ^ swz_)) = make_uint2(d01.u, d23.u); \
    } }
#define P2F32(PP, R0,R1,R2,R3) { \
    f32x4 z = {0.f,0.f,0.f,0.f}; \
    f32x4 e0_, e1_, e2_, e3_; \
    { H4U B_; B_.p[0] = __builtin_amdgcn_cvt_pkrtz(R0[0], R1[0]); \
      B_.p[1] = __builtin_amdgcn_cvt_pkrtz(R2[0], R3[0]); \
      e0_ = __builtin_amdgcn_mfma_f32_16x16x16f16(dreg##PP, B_.v, z, 0, 0, 0); } \
    { H4U B_; B_.p[0] = __builtin_amdgcn_cvt_pkrtz(R0[1], R1[1]); \
      B_.p[1] = __builtin_amdgcn_cvt_pkrtz(R2[1], R3[1]); \
      e1_ = __builtin_amdgcn_mfma_f32_16x16x16f16(dreg##PP, B_.v, z, 0, 0, 0); } \
    { H4U B_; B_.p[0] = __builtin_amdgcn_cvt_pkrtz(R0[2], R1[2]); \
      B_.p[1] = __builtin_amdgcn_cvt_pkrtz(R2[2], R3[2]); \
      e2_ = __builtin_amdgcn_mfma_f32_16x16x16f16(dreg##PP, B_.v, z, 0, 0, 0); } \
    { H4U B_; B_.p[0] = __builtin_amdgcn_cvt_pkrtz(R0[3], R1[3]); \
      B_.p[1] = __builtin_amdgcn_cvt_pkrtz(R2[3], R3[3]); \
      e3_ = __builtin_amdgcn_mfma_f32_16x16x16f16(dreg##PP, B_.v, z, 0, 0, 0); } \
    P2STORE(PP, e0_, e1_, e2_, e3_) }
    P2F32(0, fA0, fA1, fA2, fA3)
    P2F32(1, fB0, fB1, fB2, fB3)
    fA0 = *(const f32x4*)(fb + (size_t)idC.x*CIN + 4*li);
    fA1 = *(const f32x4*)(fb + (size_t)idC.y*CIN + 4*li);
    fA2 = *(const f32x4*)(fb + (size_t)idC.z*CIN + 4*li);
    fA3 = *(const f32x4*)(fb + (size_t)idC.w*CIN + 4*li);
    fB0 = *(const f32x4*)(fb + (size_t)idD.x*CIN + 4*li);
    fB1 = *(const f32x4*)(fb + (size_t)idD.y*CIN + 4*li);
    fB2 = *(const f32x4*)(fb + (size_t)idD.z*CIN + 4*li);
    fB3 = *(const f32x4*)(fb + (size_t)idD.w*CIN + 4*li);
    P2F32(2, fA0, fA1, fA2, fA3)
    P2F32(3, fB0, fB1, fB2, fB3)
#undef P2F32
#undef P2STORE
    uint4 q0 = wp[0*256], q1 = wp[1*256], q2 = wp[2*256], q3 = wp[3*256];
    uint4 q4 = wp[4*256], q5 = wp[5*256], q6 = wp[6*256], q7 = wp[7*256];
    asm volatile("s_waitcnt lgkmcnt(0)" ::: "memory");
    __builtin_amdgcn_s_barrier();
    asm volatile("" ::: "memory");
    __builtin_amdgcn_s_setprio(1);
    f32x4 a0 = {0.f,0.f,0.f,0.f}, a1 = a0, a2 = a0, a3 = a0;
    const unsigned swr = (unsigned)((li & 7) << 4);
#define AREAD(KK) (*(const h8v*)(s_agg + li*2048 + (((KK)*64 + g*16) ^ swr)))
#define MFS(KK, Q, ACC)  { H8U bu_; bu_.u4 = Q; \
    ACC = __builtin_amdgcn_mfma_f32_16x16x32_f16(AREAD(KK), bu_.v, ACC, 0, 0, 0); }
#define MFSL(KK, Q, ACC) MFS(KK, Q, ACC) Q = wp[((KK)+8)*256];
    MFSL(0, q0, a0) MFSL(1, q1, a1) MFSL(2, q2, a2) MFSL(3, q3, a3)
    MFSL(4, q4, a0) MFSL(5, q5, a1) MFSL(6, q6, a2) MFSL(7, q7, a3)
    MFSL(8, q0, a0) MFSL(9, q1, a1) MFSL(10, q2, a2) MFSL(11, q3, a3)
    MFSL(12, q4, a0) MFSL(13, q5, a1) MFSL(14, q6, a2) MFSL(15, q7, a3)
    MFSL(16, q0, a0) MFSL(17, q1, a1) MFSL(18, q2, a2) MFSL(19, q3, a3)
    MFSL(20, q4, a0) MFSL(21, q5, a1) MFSL(22, q6, a2) MFSL(23, q7, a3)
    MFS(24, q0, a0) MFS(25, q1, a1) MFS(26, q2, a2) MFS(27, q3, a3)
    MFS(28, q4, a0) MFS(29, q5, a1) MFS(30, q6, a2) MFS(31, q7, a3)
#undef MFSL
#undef MFS
#undef AREAD
    __builtin_amdgcn_s_setprio(0);
    const f32x4 acc = (a0 + a1) + (a2 + a3);
    #pragma unroll
    for (int r = 0; r < 4; ++r) {
        const int mr = g*4 + r;
        out[(size_t)(m0 + mr)*COUT + wave*16 + li] = acc[r] + biasO;
    }
}

extern "C" void kernel_launch(void* const* d_in, const int* in_sizes, int n_in,
                              void* d_out, int out_size, void* d_ws, size_t ws_size,
                              hipStream_t stream) {
    const float* features   = (const float*)d_in[0];
    const float* input_pts  = (const float*)d_in[1];
    const float* output_pts = (const float*)d_in[2];
    const float* weight     = (const float*)d_in[3];
    const float* bias       = (const float*)d_in[4];
    const float* centers    = (const float*)d_in[5];
    const float* w1         = (const float*)d_in[6];
    const float* b1         = (const float*)d_in[7];
    const float* w2         = (const float*)d_in[8];
    const float* b2         = (const float*)d_in[9];
    const float* w3         = (const float*)d_in[10];
    const float* b3         = (const float*)d_in[11];
    const int*   indices    = (const int*)d_in[12];
    float* out = (float*)d_out;
    unsigned* wsp = (unsigned*)d_ws;
    uint4* wf   = (uint4*)((char*)d_ws + WS_WF_OFF);
    uint4* fb16 = (uint4*)((char*)d_ws + WS_F16_OFF);

    const bool f16ok = ws_size >= WS_NEEDED;
    const int nconv = f16ok ? (4*NPTS*CIN) / (256*8) : 0;
    prep_kernel<<<33 + nconv, 256, 0, stream>>>(
        weight, w1, b1, centers, features, wsp, wf, fb16);

    const int total_pts = 4 * NPTS;   // 65536
    if (f16ok) {
        ptconv_pipe<<<total_pts / (PTS*ITERS), 256, 0, stream>>>(
            input_pts, output_pts, bias,
            w2, b2, w3, b3, indices, wsp, wf, (const uint2*)fb16, out);
    } else {
        ptconv_f32<<<total_pts / PTS, 256, 0, stream>>>(
            features, input_pts, output_pts, bias,
            w2, b2, w3, b3, indices, wsp, wf, out);
    }
}

// Round 13
// 50.254 us; speedup vs baseline: 2.8234x; 2.8234x over previous
//
#include <hip/hip_runtime.h>

#define NPTS 16384
#define KN   16
#define CIN  64
#define COUT 64
#define KSIZ 16
#define PTS  32      // points per block (8 waves)

typedef _Float16 h4v    __attribute__((ext_vector_type(4)));
typedef _Float16 h8v    __attribute__((ext_vector_type(8)));
typedef __fp16   fp16x2 __attribute__((ext_vector_type(2)));
typedef float    f32x4  __attribute__((ext_vector_type(4)));

union H2U { fp16x2 h; unsigned u; };
union H4U { h4v v; fp16x2 p[2]; uint2 u2; };
union H8U { h8v v; uint4 u4; };

// ws layout: [0,256) folded layer-1 (64 packed-f16 dwords); [512, 512+131072) wf;
// [131584, +8388608) f16 feature table (only if ws_size allows).
#define WS_WF_OFF   512
#define WS_F16_OFF  131584
#define WS_NEEDED   (131584ull + 8388608ull)

// prep: blocks 0..31 pack W*(1/16) into f16 B-fragment order (4 tiles per block);
// block 32 folds layer-1; blocks 33.. convert features fp32 -> f16 (RNE).
__global__ void prep_kernel(const float* __restrict__ weight,
                            const float* __restrict__ w1,
                            const float* __restrict__ b1,
                            const float* __restrict__ centers,
                            const float* __restrict__ features,
                            unsigned* __restrict__ wsp,
                            uint4* __restrict__ wf,
                            uint4* __restrict__ fb16) {
    const int b = blockIdx.x;
    const int t = threadIdx.x;
    if (b < 32) {
        // slot s (0..1023) <-> (j,c): j = s>>6, c = s&63 (byte 2s in [j][c] f16 row).
        // Fragment: K-step kk, n-tile nt, lane l, elem e -> s = kk*32 + (l>>4)*8 + e,
        // o = nt*16 + (l&15). Consumer uses identical maps -> k-perm-invariant.
        const int bp = b*4 + (t>>6);
        const int kk = bp >> 2, nt = bp & 3;
        const int l = t & 63, li = l & 15, g = l >> 4;
        unsigned short u[8];
        #pragma unroll
        for (int e = 0; e < 8; ++e) {
            int s = kk*32 + g*8 + e;
            int j = s >> 6;
            int c = s & 63;
            union { _Float16 h; unsigned short s16; } cv;
            cv.h = (_Float16)(weight[(c*16 + j)*64 + nt*16 + li] * 0.0625f);
            u[e] = cv.s16;
        }
        uint4 v;
        v.x = u[0] | ((unsigned)u[1] << 16);
        v.y = u[2] | ((unsigned)u[3] << 16);
        v.z = u[4] | ((unsigned)u[5] << 16);
        v.w = u[6] | ((unsigned)u[7] << 16);
        wf[(kk*4 + nt)*64 + l] = v;
    } else if (b == 32) {
        __shared__ float tmp[4][32];
        if (t < 32) {
            int n = t;
            float s0 = 0.f, s1 = 0.f, s2 = 0.f, bf = b1[n];
            for (int s = 0; s < KSIZ; ++s) {
                float a0 = w1[(0*KSIZ + s)*32 + n];
                float a1 = w1[(1*KSIZ + s)*32 + n];
                float a2 = w1[(2*KSIZ + s)*32 + n];
                s0 += a0; s1 += a1; s2 += a2;
                bf -= centers[0*KSIZ+s]*a0 + centers[1*KSIZ+s]*a1 + centers[2*KSIZ+s]*a2;
            }
            tmp[0][n] = s0; tmp[1][n] = s1; tmp[2][n] = s2; tmp[3][n] = bf;
        }
        __syncthreads();
        if (t < 64) {
            const int row = t >> 4, q = t & 15;
            union { _Float16 h[2]; unsigned u; } pk;
            pk.h[0] = (_Float16)tmp[row][2*q];
            pk.h[1] = (_Float16)tmp[row][2*q+1];
            wsp[row*16 + q] = pk.u;
        }
    } else {
        const size_t e0 = ((size_t)(b - 33)*256 + t) * 8;
        const float4 f0 = *(const float4*)(features + e0);
        const float4 f1 = *(const float4*)(features + e0 + 4);
        union { _Float16 h[8]; uint4 v; } o;
        o.h[0] = (_Float16)f0.x; o.h[1] = (_Float16)f0.y;
        o.h[2] = (_Float16)f0.z; o.h[3] = (_Float16)f0.w;
        o.h[4] = (_Float16)f1.x; o.h[5] = (_Float16)f1.y;
        o.h[6] = (_Float16)f1.z; o.h[7] = (_Float16)f1.w;
        fb16[e0 >> 3] = o.v;
    }
}

// FM=1: f16 feature table; FM=0: fp32 features (fallback, half-split gathers).
// 8 waves: wave w = (h = w>>2 point-subtile, n = w&3 output-column quarter).
// Waves {n, n+4} share the same wf slices -> L1 reuse; W L2 traffic per point halves.
template<int FM>
__global__ __launch_bounds__(512, 4)
void ptconv_kernel(const float* __restrict__ features,
                   const float* __restrict__ input_pts,
                   const float* __restrict__ output_pts,
                   const float* __restrict__ bias,
                   const float* __restrict__ w2,
                   const float* __restrict__ b2,
                   const float* __restrict__ w3,
                   const float* __restrict__ b3,
                   const int*   __restrict__ indices,
                   const unsigned* __restrict__ folded,
                   const uint4* __restrict__ wf,
                   const uint2* __restrict__ fb16,   // f16 features [n][c]
                   float* __restrict__ out) {
    // LDS = 65536 -> 2 blocks/CU (16 waves/CU). s_agg[32 pts][2048B], rows [j][c] f16,
    // byte offset XOR-swizzled by ((point&7)<<4) on both store and read.
    // Wave w's 8KB region [w*8192,(w+1)*8192) (= its own points 4w..4w+3) also holds
    // its h1 rows (l*80B) during layers 1-3 (wave-private alias, single barrier).
    __shared__ __align__(16) char smem[65536];
    char* s_agg = smem;

    const int t    = threadIdx.x;
    const int l    = t & 63;
    const int wave = t >> 6;          // 0..7
    const int li   = l & 15;
    const int g    = l >> 4;
    const int h    = wave >> 2;       // point-subtile for phase 3
    const int nq   = wave & 3;        // n-quarter for phase 3
    const int m0   = blockIdx.x * PTS;
    const int bbk  = m0 >> 14;
    const int mloc = m0 & (NPTS-1);   // batch-local base

    const int*   idxB  = indices    + (size_t)bbk*NPTS*KN;
    const float* ptsB  = input_pts  + (size_t)bbk*NPTS*3;
    const float* optsB = output_pts + (size_t)bbk*NPTS*3;
    const float* fb    = features + (size_t)bbk*NPTS*CIN;
    const uint2* fb16B = fb16 + (size_t)bbk*NPTS*(CIN/4);

    // ---- rel chain: per-thread (point p1, neighbor k1); 512 thr = 32x16 ----
    const int p1 = t >> 4, k1 = t & 15;
    const int nn = mloc + p1;
    const int idxv = idxB[nn*KN + k1];
    const float cop0 = optsB[nn*3+0], cop1 = optsB[nn*3+1], cop2 = optsB[nn*3+2];
    const float cip0 = ptsB[(size_t)idxv*3+0];
    const float cip1 = ptsB[(size_t)idxv*3+1];
    const float cip2 = ptsB[(size_t)idxv*3+2];

    // ---- neighbor index quads (wave owns points 4w..4w+3) + feature gathers ----
    const int4 idA = *(const int4*)(idxB + (mloc + wave*4+0)*KN + 4*g);
    const int4 idB = *(const int4*)(idxB + (mloc + wave*4+1)*KN + 4*g);
    const int4 idC = *(const int4*)(idxB + (mloc + wave*4+2)*KN + 4*g);
    const int4 idD = *(const int4*)(idxB + (mloc + wave*4+3)*KN + 4*g);

    H4U gA0, gA1, gA2, gA3, gB0, gB1, gB2, gB3;
    H4U gC0, gC1, gC2, gC3, gD0, gD1, gD2, gD3;
    f32x4 fA0, fA1, fA2, fA3, fB0, fB1, fB2, fB3;
    if constexpr (FM == 1) {
        gA0.u2 = fb16B[(size_t)idA.x*16 + li]; gA1.u2 = fb16B[(size_t)idA.y*16 + li];
        gA2.u2 = fb16B[(size_t)idA.z*16 + li]; gA3.u2 = fb16B[(size_t)idA.w*16 + li];
        gB0.u2 = fb16B[(size_t)idB.x*16 + li]; gB1.u2 = fb16B[(size_t)idB.y*16 + li];
        gB2.u2 = fb16B[(size_t)idB.z*16 + li]; gB3.u2 = fb16B[(size_t)idB.w*16 + li];
        gC0.u2 = fb16B[(size_t)idC.x*16 + li]; gC1.u2 = fb16B[(size_t)idC.y*16 + li];
        gC2.u2 = fb16B[(size_t)idC.z*16 + li]; gC3.u2 = fb16B[(size_t)idC.w*16 + li];
        gD0.u2 = fb16B[(size_t)idD.x*16 + li]; gD1.u2 = fb16B[(size_t)idD.y*16 + li];
        gD2.u2 = fb16B[(size_t)idD.z*16 + li]; gD3.u2 = fb16B[(size_t)idD.w*16 + li];
    } else {
        fA0 = *(const f32x4*)(fb + (size_t)idA.x*CIN + 4*li);
        fA1 = *(const f32x4*)(fb + (size_t)idA.y*CIN + 4*li);
        fA2 = *(const f32x4*)(fb + (size_t)idA.z*CIN + 4*li);
        fA3 = *(const f32x4*)(fb + (size_t)idA.w*CIN + 4*li);
        fB0 = *(const f32x4*)(fb + (size_t)idB.x*CIN + 4*li);
        fB1 = *(const f32x4*)(fb + (size_t)idB.y*CIN + 4*li);
        fB2 = *(const f32x4*)(fb + (size_t)idB.z*CIN + 4*li);
        fB3 = *(const f32x4*)(fb + (size_t)idB.w*CIN + 4*li);
    }

    // ---- weight fragments / biases ----
    h8v w2f; h4v w3f;
    #pragma unroll
    for (int e = 0; e < 8; ++e) w2f[e] = (_Float16)w2[(8*g+e)*16 + li];
    #pragma unroll
    for (int e = 0; e < 4; ++e) w3f[e] = (_Float16)w3[(4*g+e)*16 + li];
    const f32x4 b2v4  = *(const f32x4*)(b2 + 4*g);
    const float b3v   = b3[li];
    const float biasO = bias[nq*16 + li];
    const uint4* wp   = wf + nq*64 + l;

    // ---- layer 1: packed f16 (uniform params -> scalar loads) ----
    {
        const __fp16 r0h = (__fp16)(cip0-cop0);
        const __fp16 r1h = (__fp16)(cip1-cop1);
        const __fp16 r2h = (__fp16)(cip2-cop2);
        fp16x2 r0p = {r0h, r0h}, r1p = {r1h, r1h}, r2p = {r2h, r2h};
        const fp16x2 zz = {(__fp16)0.f, (__fp16)0.f};
        uint4* dst = (uint4*)(smem + wave*8192 + l*80);
        unsigned o8[8];
        #pragma unroll
        for (int half = 0; half < 2; ++half) {
            #pragma unroll
            for (int qq = 0; qq < 8; ++qq) {
                const int q = half*8 + qq;
                H2U a, u0, u1, u2;
                a.u  = folded[48+q];
                u0.u = folded[q];
                u1.u = folded[16+q];
                u2.u = folded[32+q];
                fp16x2 acc = r0p*u0.h + a.h;
                acc = r1p*u1.h + acc;
                acc = r2p*u2.h + acc;
                acc = __builtin_elementwise_max(acc, zz);
                H2U o; o.h = acc; o8[qq] = o.u;
            }
            dst[half*2+0] = make_uint4(o8[0], o8[1], o8[2], o8[3]);
            dst[half*2+1] = make_uint4(o8[4], o8[5], o8[6], o8[7]);
        }
    }

    // ---- layers 2+3 on MFMA, register-chained ----
    h4v dreg0, dreg1, dreg2, dreg3;
#define L23(PP, DREG) { \
    h8v B2 = *(const h8v*)(smem + wave*8192 + ((PP)*16 + li)*80 + g*16); \
    f32x4 a2 = b2v4; \
    a2 = __builtin_amdgcn_mfma_f32_16x16x32_f16(w2f, B2, a2, 0, 0, 0); \
    H4U A3; \
    A3.p[0] = __builtin_amdgcn_cvt_pkrtz(fmaxf(a2[0],0.f), fmaxf(a2[1],0.f)); \
    A3.p[1] = __builtin_amdgcn_cvt_pkrtz(fmaxf(a2[2],0.f), fmaxf(a2[3],0.f)); \
    f32x4 a3 = {b3v, b3v, b3v, b3v}; \
    a3 = __builtin_amdgcn_mfma_f32_16x16x16f16(A3.v, w3f, a3, 0, 0, 0); \
    H4U Dv; \
    Dv.p[0] = __builtin_amdgcn_cvt_pkrtz(fmaxf(a3[0],0.f), fmaxf(a3[1],0.f)); \
    Dv.p[1] = __builtin_amdgcn_cvt_pkrtz(fmaxf(a3[2],0.f), fmaxf(a3[3],0.f)); \
    DREG = Dv.v; }
    L23(0, dreg0) L23(1, dreg1) L23(2, dreg2) L23(3, dreg3)
#undef L23

    // ---- phase 2: agg[j][c] = mfma(dreg, features), K=16; swizzled store ----
#define P2STORE(PP, E0,E1,E2,E3) { \
    const int pix_ = wave*4 + (PP); \
    const unsigned swz_ = (unsigned)((pix_ & 7) << 4); \
    char* ab_ = s_agg + pix_*2048; \
    _Pragma("unroll") \
    for (int r = 0; r < 4; ++r) { \
        H2U d01, d23; \
        d01.h = __builtin_amdgcn_cvt_pkrtz(E0[r], E1[r]); \
        d23.h = __builtin_amdgcn_cvt_pkrtz(E2[r], E3[r]); \
        *(uint2*)(ab_ + ((unsigned)((4*g + r)*128 + 8*li) ^ swz_)) = \
            make_uint2(d01.u, d23.u); \
    } }

    if constexpr (FM == 1) {
#define P2F16(PP, R0,R1,R2,R3) { \
        f32x4 z = {0.f,0.f,0.f,0.f}; \
        f32x4 e0_, e1_, e2_, e3_; \
        { H4U B_; B_.v = (h4v){R0.v[0], R1.v[0], R2.v[0], R3.v[0]}; \
          e0_ = __builtin_amdgcn_mfma_f32_16x16x16f16(dreg##PP, B_.v, z, 0, 0, 0); } \
        { H4U B_; B_.v = (h4v){R0.v[1], R1.v[1], R2.v[1], R3.v[1]}; \
          e1_ = __builtin_amdgcn_mfma_f32_16x16x16f16(dreg##PP, B_.v, z, 0, 0, 0); } \
        { H4U B_; B_.v = (h4v){R0.v[2], R1.v[2], R2.v[2], R3.v[2]}; \
          e2_ = __builtin_amdgcn_mfma_f32_16x16x16f16(dreg##PP, B_.v, z, 0, 0, 0); } \
        { H4U B_; B_.v = (h4v){R0.v[3], R1.v[3], R2.v[3], R3.v[3]}; \
          e3_ = __builtin_amdgcn_mfma_f32_16x16x16f16(dreg##PP, B_.v, z, 0, 0, 0); } \
        P2STORE(PP, e0_, e1_, e2_, e3_) }
        P2F16(0, gA0, gA1, gA2, gA3)
        P2F16(1, gB0, gB1, gB2, gB3)
        P2F16(2, gC0, gC1, gC2, gC3)
        P2F16(3, gD0, gD1, gD2, gD3)
#undef P2F16
    } else {
#define P2F32(PP, R0,R1,R2,R3) { \
        f32x4 z = {0.f,0.f,0.f,0.f}; \
        f32x4 e0_, e1_, e2_, e3_; \
        { H4U B_; B_.p[0] = __builtin_amdgcn_cvt_pkrtz(R0[0], R1[0]); \
          B_.p[1] = __builtin_amdgcn_cvt_pkrtz(R2[0], R3[0]); \
          e0_ = __builtin_amdgcn_mfma_f32_16x16x16f16(dreg##PP, B_.v, z, 0, 0, 0); } \
        { H4U B_; B_.p[0] = __builtin_amdgcn_cvt_pkrtz(R0[1], R1[1]); \
          B_.p[1] = __builtin_amdgcn_cvt_pkrtz(R2[1], R3[1]); \
          e1_ = __builtin_amdgcn_mfma_f32_16x16x16f16(dreg##PP, B_.v, z, 0, 0, 0); } \
        { H4U B_; B_.p[0] = __builtin_amdgcn_cvt_pkrtz(R0[2], R1[2]); \
          B_.p[1] = __builtin_amdgcn_cvt_pkrtz(R2[2], R3[2]); \
          e2_ = __builtin_amdgcn_mfma_f32_16x16x16f16(dreg##PP, B_.v, z, 0, 0, 0); } \
        { H4U B_; B_.p[0] = __builtin_amdgcn_cvt_pkrtz(R0[3], R1[3]); \
          B_.p[1] = __builtin_amdgcn_cvt_pkrtz(R2[3], R3[3]); \
          e3_ = __builtin_amdgcn_mfma_f32_16x16x16f16(dreg##PP, B_.v, z, 0, 0, 0); } \
        P2STORE(PP, e0_, e1_, e2_, e3_) }
        P2F32(0, fA0, fA1, fA2, fA3)
        P2F32(1, fB0, fB1, fB2, fB3)
        fA0 = *(const f32x4*)(fb + (size_t)idC.x*CIN + 4*li);
        fA1 = *(const f32x4*)(fb + (size_t)idC.y*CIN + 4*li);
        fA2 = *(const f32x4*)(fb + (size_t)idC.z*CIN + 4*li);
        fA3 = *(const f32x4*)(fb + (size_t)idC.w*CIN + 4*li);
        fB0 = *(const f32x4*)(fb + (size_t)idD.x*CIN + 4*li);
        fB1 = *(const f32x4*)(fb + (size_t)idD.y*CIN + 4*li);
        fB2 = *(const f32x4*)(fb + (size_t)idD.z*CIN + 4*li);
        fB3 = *(const f32x4*)(fb + (size_t)idD.w*CIN + 4*li);
        P2F32(2, fA0, fA1, fA2, fA3)
        P2F32(3, fB0, fB1, fB2, fB3)
#undef P2F32
    }
#undef P2STORE

    // ---- issue first 8 wf fragments (may stay in flight across the barrier) ----
    uint4 q0 = wp[0*256], q1 = wp[1*256], q2 = wp[2*256], q3 = wp[3*256];
    uint4 q4 = wp[4*256], q5 = wp[5*256], q6 = wp[6*256], q7 = wp[7*256];

    // raw barrier: LDS drained (lgkmcnt) but vmcnt NOT drained
    asm volatile("s_waitcnt lgkmcnt(0)" ::: "memory");
    __builtin_amdgcn_s_barrier();
    asm volatile("" ::: "memory");

    // ---- phase 3: out[subtile h: 16 pts][n-quarter nq] = AGG x Wf ----
    // 4 independent accumulators; 8-deep rolling wf register window.
    __builtin_amdgcn_s_setprio(1);
    f32x4 a0 = {0.f,0.f,0.f,0.f}, a1 = a0, a2 = a0, a3 = a0;
    const unsigned swr = (unsigned)((li & 7) << 4);
#define AREAD(KK) (*(const h8v*)(s_agg + (h*16 + li)*2048 + (((KK)*64 + g*16) ^ swr)))
#define MFS(KK, Q, ACC)  { H8U bu_; bu_.u4 = Q; \
    ACC = __builtin_amdgcn_mfma_f32_16x16x32_f16(AREAD(KK), bu_.v, ACC, 0, 0, 0); }
#define MFSL(KK, Q, ACC) MFS(KK, Q, ACC) Q = wp[((KK)+8)*256];
    MFSL(0, q0, a0) MFSL(1, q1, a1) MFSL(2, q2, a2) MFSL(3, q3, a3)
    MFSL(4, q4, a0) MFSL(5, q5, a1) MFSL(6, q6, a2) MFSL(7, q7, a3)
    MFSL(8, q0, a0) MFSL(9, q1, a1) MFSL(10, q2, a2) MFSL(11, q3, a3)
    MFSL(12, q4, a0) MFSL(13, q5, a1) MFSL(14, q6, a2) MFSL(15, q7, a3)
    MFSL(16, q0, a0) MFSL(17, q1, a1) MFSL(18, q2, a2) MFSL(19, q3, a3)
    MFSL(20, q4, a0) MFSL(21, q5, a1) MFSL(22, q6, a2) MFSL(23, q7, a3)
    MFS(24, q0, a0) MFS(25, q1, a1) MFS(26, q2, a2) MFS(27, q3, a3)
    MFS(28, q4, a0) MFS(29, q5, a1) MFS(30, q6, a2) MFS(31, q7, a3)
#undef MFSL
#undef MFS
#undef AREAD
    __builtin_amdgcn_s_setprio(0);

    const f32x4 acc = (a0 + a1) + (a2 + a3);
    #pragma unroll
    for (int r = 0; r < 4; ++r) {
        const int mr = h*16 + g*4 + r;
        out[(size_t)(m0 + mr)*COUT + nq*16 + li] = acc[r] + biasO;
    }
}

extern "C" void kernel_launch(void* const* d_in, const int* in_sizes, int n_in,
                              void* d_out, int out_size, void* d_ws, size_t ws_size,
                              hipStream_t stream) {
    const float* features   = (const float*)d_in[0];
    const float* input_pts  = (const float*)d_in[1];
    const float* output_pts = (const float*)d_in[2];
    const float* weight     = (const float*)d_in[3];
    const float* bias       = (const float*)d_in[4];
    const float* centers    = (const float*)d_in[5];
    const float* w1         = (const float*)d_in[6];
    const float* b1         = (const float*)d_in[7];
    const float* w2         = (const float*)d_in[8];
    const float* b2         = (const float*)d_in[9];
    const float* w3         = (const float*)d_in[10];
    const float* b3         = (const float*)d_in[11];
    const int*   indices    = (const int*)d_in[12];
    float* out = (float*)d_out;
    unsigned* wsp = (unsigned*)d_ws;
    uint4* wf   = (uint4*)((char*)d_ws + WS_WF_OFF);
    uint4* fb16 = (uint4*)((char*)d_ws + WS_F16_OFF);

    const bool f16ok = ws_size >= WS_NEEDED;
    const int nconv = f16ok ? (4*NPTS*CIN) / (256*8) : 0;
    prep_kernel<<<33 + nconv, 256, 0, stream>>>(
        weight, w1, b1, centers, features, wsp, wf, fb16);

    const int total_pts = 4 * NPTS;   // 65536
    if (f16ok) {
        ptconv_kernel<1><<<total_pts / PTS, 512, 0, stream>>>(
            features, input_pts, output_pts, bias,
            w2, b2, w3, b3, indices, wsp, wf, (const uint2*)fb16, out);
    } else {
        ptconv_kernel<0><<<total_pts / PTS, 512, 0, stream>>>(
            features, input_pts, output_pts, bias,
            w2, b2, w3, b3, indices, wsp, wf, (const uint2*)fb16, out);
    }
}

// Round 14
// 42.617 us; speedup vs baseline: 3.3293x; 1.1792x over previous
//
#include <hip/hip_runtime.h>

#define NPTS 16384
#define KN   16
#define CIN  64
#define COUT 64
#define KSIZ 16
#define PTS  32      // points per block (8 waves)

typedef _Float16 h4v    __attribute__((ext_vector_type(4)));
typedef _Float16 h8v    __attribute__((ext_vector_type(8)));
typedef __fp16   fp16x2 __attribute__((ext_vector_type(2)));
typedef float    f32x4  __attribute__((ext_vector_type(4)));

union H2U { fp16x2 h; unsigned u; };
union H4U { h4v v; fp16x2 p[2]; uint2 u2; };
union H8U { h8v v; uint4 u4; };

#define WS_WF_OFF   512
#define WS_F16_OFF  131584
#define WS_NEEDED   (131584ull + 8388608ull)

// prep: blocks 0..31 pack W*(1/16) into f16 B-fragment order; block 32 folds
// layer-1; blocks 33.. convert features fp32 -> f16 (RNE).
__global__ void prep_kernel(const float* __restrict__ weight,
                            const float* __restrict__ w1,
                            const float* __restrict__ b1,
                            const float* __restrict__ centers,
                            const float* __restrict__ features,
                            unsigned* __restrict__ wsp,
                            uint4* __restrict__ wf,
                            uint4* __restrict__ fb16) {
    const int b = blockIdx.x;
    const int t = threadIdx.x;
    if (b < 32) {
        // slot s (0..1023) <-> (j,c): j = s>>6, c = s&63 (byte 2s in [j][c] f16 row).
        // Fragment: K-step kk, n-tile nt, lane l, elem e -> s = kk*32 + (l>>4)*8 + e,
        // o = nt*16 + (l&15). Consumer uses identical maps -> k-perm-invariant.
        const int bp = b*4 + (t>>6);
        const int kk = bp >> 2, nt = bp & 3;
        const int l = t & 63, li = l & 15, g = l >> 4;
        unsigned short u[8];
        #pragma unroll
        for (int e = 0; e < 8; ++e) {
            int s = kk*32 + g*8 + e;
            int j = s >> 6;
            int c = s & 63;
            union { _Float16 h; unsigned short s16; } cv;
            cv.h = (_Float16)(weight[(c*16 + j)*64 + nt*16 + li] * 0.0625f);
            u[e] = cv.s16;
        }
        uint4 v;
        v.x = u[0] | ((unsigned)u[1] << 16);
        v.y = u[2] | ((unsigned)u[3] << 16);
        v.z = u[4] | ((unsigned)u[5] << 16);
        v.w = u[6] | ((unsigned)u[7] << 16);
        wf[(kk*4 + nt)*64 + l] = v;
    } else if (b == 32) {
        __shared__ float tmp[4][32];
        if (t < 32) {
            int n = t;
            float s0 = 0.f, s1 = 0.f, s2 = 0.f, bf = b1[n];
            for (int s = 0; s < KSIZ; ++s) {
                float a0 = w1[(0*KSIZ + s)*32 + n];
                float a1 = w1[(1*KSIZ + s)*32 + n];
                float a2 = w1[(2*KSIZ + s)*32 + n];
                s0 += a0; s1 += a1; s2 += a2;
                bf -= centers[0*KSIZ+s]*a0 + centers[1*KSIZ+s]*a1 + centers[2*KSIZ+s]*a2;
            }
            tmp[0][n] = s0; tmp[1][n] = s1; tmp[2][n] = s2; tmp[3][n] = bf;
        }
        __syncthreads();
        if (t < 64) {
            const int row = t >> 4, q = t & 15;
            union { _Float16 h[2]; unsigned u; } pk;
            pk.h[0] = (_Float16)tmp[row][2*q];
            pk.h[1] = (_Float16)tmp[row][2*q+1];
            wsp[row*16 + q] = pk.u;
        }
    } else {
        const size_t e0 = ((size_t)(b - 33)*256 + t) * 8;
        const float4 f0 = *(const float4*)(features + e0);
        const float4 f1 = *(const float4*)(features + e0 + 4);
        union { _Float16 h[8]; uint4 v; } o;
        o.h[0] = (_Float16)f0.x; o.h[1] = (_Float16)f0.y;
        o.h[2] = (_Float16)f0.z; o.h[3] = (_Float16)f0.w;
        o.h[4] = (_Float16)f1.x; o.h[5] = (_Float16)f1.y;
        o.h[6] = (_Float16)f1.z; o.h[7] = (_Float16)f1.w;
        fb16[e0 >> 3] = o.v;
    }
}

// FM=1: f16 feature table; FM=0: fp32 features.
// 8 waves: phases 1-2: wave w owns points 4w..4w+3.
// Phase 3: wave w = (nq = w&3, kkh = w>>2); computes PARTIALS for both 16-pt
// subtiles over kk in [kkh*16, kkh*16+16). Pairs (w, w+4) reduce via LDS.
// -> each wf dword read exactly once per block (guaranteed dedup).
template<int FM>
__global__ __launch_bounds__(512, 4)
void ptconv_kernel(const float* __restrict__ features,
                   const float* __restrict__ input_pts,
                   const float* __restrict__ output_pts,
                   const float* __restrict__ bias,
                   const float* __restrict__ w2,
                   const float* __restrict__ b2,
                   const float* __restrict__ w3,
                   const float* __restrict__ b3,
                   const int*   __restrict__ indices,
                   const unsigned* __restrict__ folded,
                   const uint4* __restrict__ wf,
                   const uint2* __restrict__ fb16,
                   float* __restrict__ out) {
    // LDS 65536: s_agg[32 pts][2048B] rows [j][c] f16, XOR-swizzled by ((pt&7)<<4)
    // on store and read. Wave w's 8KB region doubles as its h1 scratch (l*80B).
    // After phase 3 the first 8KB is reused for the pair-reduction partials.
    __shared__ __align__(16) char smem[65536];
    char* s_agg = smem;

    const int t    = threadIdx.x;
    const int l    = t & 63;
    const int wave = t >> 6;          // 0..7
    const int li   = l & 15;
    const int g    = l >> 4;
    const int nq   = wave & 3;        // output-column quarter
    const int kkh  = wave >> 2;       // kk-half for phase 3
    const int m0   = blockIdx.x * PTS;
    const int bbk  = m0 >> 14;
    const int mloc = m0 & (NPTS-1);

    const int*   idxB  = indices    + (size_t)bbk*NPTS*KN;
    const float* ptsB  = input_pts  + (size_t)bbk*NPTS*3;
    const float* optsB = output_pts + (size_t)bbk*NPTS*3;
    const float* fb    = features + (size_t)bbk*NPTS*CIN;
    const uint2* fb16B = fb16 + (size_t)bbk*NPTS*(CIN/4);

    // ---- rel chain: per-thread (point p1, neighbor k1); float3 loads ----
    const int p1 = t >> 4, k1 = t & 15;
    const int nn = mloc + p1;
    const int idxv = idxB[nn*KN + k1];
    const float3 opv = *(const float3*)(optsB + nn*3);
    const float3 ipv = *(const float3*)(ptsB + (size_t)idxv*3);

    // ---- neighbor index quads + feature gathers ----
    const int4 idA = *(const int4*)(idxB + (mloc + wave*4+0)*KN + 4*g);
    const int4 idB = *(const int4*)(idxB + (mloc + wave*4+1)*KN + 4*g);
    const int4 idC = *(const int4*)(idxB + (mloc + wave*4+2)*KN + 4*g);
    const int4 idD = *(const int4*)(idxB + (mloc + wave*4+3)*KN + 4*g);

    H4U gA0, gA1, gA2, gA3, gB0, gB1, gB2, gB3;
    H4U gC0, gC1, gC2, gC3, gD0, gD1, gD2, gD3;
    f32x4 fA0, fA1, fA2, fA3, fB0, fB1, fB2, fB3;
    if constexpr (FM == 1) {
        gA0.u2 = fb16B[(size_t)idA.x*16 + li]; gA1.u2 = fb16B[(size_t)idA.y*16 + li];
        gA2.u2 = fb16B[(size_t)idA.z*16 + li]; gA3.u2 = fb16B[(size_t)idA.w*16 + li];
        gB0.u2 = fb16B[(size_t)idB.x*16 + li]; gB1.u2 = fb16B[(size_t)idB.y*16 + li];
        gB2.u2 = fb16B[(size_t)idB.z*16 + li]; gB3.u2 = fb16B[(size_t)idB.w*16 + li];
        gC0.u2 = fb16B[(size_t)idC.x*16 + li]; gC1.u2 = fb16B[(size_t)idC.y*16 + li];
        gC2.u2 = fb16B[(size_t)idC.z*16 + li]; gC3.u2 = fb16B[(size_t)idC.w*16 + li];
        gD0.u2 = fb16B[(size_t)idD.x*16 + li]; gD1.u2 = fb16B[(size_t)idD.y*16 + li];
        gD2.u2 = fb16B[(size_t)idD.z*16 + li]; gD3.u2 = fb16B[(size_t)idD.w*16 + li];
    } else {
        fA0 = *(const f32x4*)(fb + (size_t)idA.x*CIN + 4*li);
        fA1 = *(const f32x4*)(fb + (size_t)idA.y*CIN + 4*li);
        fA2 = *(const f32x4*)(fb + (size_t)idA.z*CIN + 4*li);
        fA3 = *(const f32x4*)(fb + (size_t)idA.w*CIN + 4*li);
        fB0 = *(const f32x4*)(fb + (size_t)idB.x*CIN + 4*li);
        fB1 = *(const f32x4*)(fb + (size_t)idB.y*CIN + 4*li);
        fB2 = *(const f32x4*)(fb + (size_t)idB.z*CIN + 4*li);
        fB3 = *(const f32x4*)(fb + (size_t)idB.w*CIN + 4*li);
    }

    // ---- phase-3 wf preload (independent; issued early for latency slack) ----
    const uint4* wp = wf + nq*64 + l;
    uint4 q0 = wp[(kkh*16+0)*256], q1 = wp[(kkh*16+1)*256];
    uint4 q2 = wp[(kkh*16+2)*256], q3 = wp[(kkh*16+3)*256];
    uint4 q4 = wp[(kkh*16+4)*256], q5 = wp[(kkh*16+5)*256];
    uint4 q6 = wp[(kkh*16+6)*256], q7 = wp[(kkh*16+7)*256];

    // ---- weight fragments / biases ----
    h8v w2f; h4v w3f;
    #pragma unroll
    for (int e = 0; e < 8; ++e) w2f[e] = (_Float16)w2[(8*g+e)*16 + li];
    #pragma unroll
    for (int e = 0; e < 4; ++e) w3f[e] = (_Float16)w3[(4*g+e)*16 + li];
    const f32x4 b2v4  = *(const f32x4*)(b2 + 4*g);
    const float b3v   = b3[li];
    const float biasO = bias[nq*16 + li];

    // ---- layer 1: packed f16 (uniform params -> scalar loads) ----
    {
        const __fp16 r0h = (__fp16)(ipv.x - opv.x);
        const __fp16 r1h = (__fp16)(ipv.y - opv.y);
        const __fp16 r2h = (__fp16)(ipv.z - opv.z);
        fp16x2 r0p = {r0h, r0h}, r1p = {r1h, r1h}, r2p = {r2h, r2h};
        const fp16x2 zz = {(__fp16)0.f, (__fp16)0.f};
        uint4* dst = (uint4*)(smem + wave*8192 + l*80);
        unsigned o8[8];
        #pragma unroll
        for (int half = 0; half < 2; ++half) {
            #pragma unroll
            for (int qq = 0; qq < 8; ++qq) {
                const int q = half*8 + qq;
                H2U a, u0, u1, u2;
                a.u  = folded[48+q];
                u0.u = folded[q];
                u1.u = folded[16+q];
                u2.u = folded[32+q];
                fp16x2 acc = r0p*u0.h + a.h;
                acc = r1p*u1.h + acc;
                acc = r2p*u2.h + acc;
                acc = __builtin_elementwise_max(acc, zz);
                H2U o; o.h = acc; o8[qq] = o.u;
            }
            dst[half*2+0] = make_uint4(o8[0], o8[1], o8[2], o8[3]);
            dst[half*2+1] = make_uint4(o8[4], o8[5], o8[6], o8[7]);
        }
    }

    // ---- layers 2+3 on MFMA, register-chained ----
    h4v dreg0, dreg1, dreg2, dreg3;
#define L23(PP, DREG) { \
    h8v B2 = *(const h8v*)(smem + wave*8192 + ((PP)*16 + li)*80 + g*16); \
    f32x4 a2 = b2v4; \
    a2 = __builtin_amdgcn_mfma_f32_16x16x32_f16(w2f, B2, a2, 0, 0, 0); \
    H4U A3; \
    A3.p[0] = __builtin_amdgcn_cvt_pkrtz(fmaxf(a2[0],0.f), fmaxf(a2[1],0.f)); \
    A3.p[1] = __builtin_amdgcn_cvt_pkrtz(fmaxf(a2[2],0.f), fmaxf(a2[3],0.f)); \
    f32x4 a3 = {b3v, b3v, b3v, b3v}; \
    a3 = __builtin_amdgcn_mfma_f32_16x16x16f16(A3.v, w3f, a3, 0, 0, 0); \
    H4U Dv; \
    Dv.p[0] = __builtin_amdgcn_cvt_pkrtz(fmaxf(a3[0],0.f), fmaxf(a3[1],0.f)); \
    Dv.p[1] = __builtin_amdgcn_cvt_pkrtz(fmaxf(a3[2],0.f), fmaxf(a3[3],0.f)); \
    DREG = Dv.v; }
    L23(0, dreg0) L23(1, dreg1) L23(2, dreg2) L23(3, dreg3)
#undef L23

    // ---- phase 2: agg[j][c] = mfma(dreg, features), K=16; swizzled store ----
#define P2STORE(PP, E0,E1,E2,E3) { \
    const int pix_ = wave*4 + (PP); \
    const unsigned swz_ = (unsigned)((pix_ & 7) << 4); \
    char* ab_ = s_agg + pix_*2048; \
    _Pragma("unroll") \
    for (int r = 0; r < 4; ++r) { \
        H2U d01, d23; \
        d01.h = __builtin_amdgcn_cvt_pkrtz(E0[r], E1[r]); \
        d23.h = __builtin_amdgcn_cvt_pkrtz(E2[r], E3[r]); \
        *(uint2*)(ab_ + ((unsigned)((4*g + r)*128 + 8*li) ^ swz_)) = \
            make_uint2(d01.u, d23.u); \
    } }

    if constexpr (FM == 1) {
#define P2F16(PP, R0,R1,R2,R3) { \
        f32x4 z = {0.f,0.f,0.f,0.f}; \
        f32x4 e0_, e1_, e2_, e3_; \
        { H4U B_; B_.v = (h4v){R0.v[0], R1.v[0], R2.v[0], R3.v[0]}; \
          e0_ = __builtin_amdgcn_mfma_f32_16x16x16f16(dreg##PP, B_.v, z, 0, 0, 0); } \
        { H4U B_; B_.v = (h4v){R0.v[1], R1.v[1], R2.v[1], R3.v[1]}; \
          e1_ = __builtin_amdgcn_mfma_f32_16x16x16f16(dreg##PP, B_.v, z, 0, 0, 0); } \
        { H4U B_; B_.v = (h4v){R0.v[2], R1.v[2], R2.v[2], R3.v[2]}; \
          e2_ = __builtin_amdgcn_mfma_f32_16x16x16f16(dreg##PP, B_.v, z, 0, 0, 0); } \
        { H4U B_; B_.v = (h4v){R0.v[3], R1.v[3], R2.v[3], R3.v[3]}; \
          e3_ = __builtin_amdgcn_mfma_f32_16x16x16f16(dreg##PP, B_.v, z, 0, 0, 0); } \
        P2STORE(PP, e0_, e1_, e2_, e3_) }
        P2F16(0, gA0, gA1, gA2, gA3)
        P2F16(1, gB0, gB1, gB2, gB3)
        P2F16(2, gC0, gC1, gC2, gC3)
        P2F16(3, gD0, gD1, gD2, gD3)
#undef P2F16
    } else {
#define P2F32(PP, R0,R1,R2,R3) { \
        f32x4 z = {0.f,0.f,0.f,0.f}; \
        f32x4 e0_, e1_, e2_, e3_; \
        { H4U B_; B_.p[0] = __builtin_amdgcn_cvt_pkrtz(R0[0], R1[0]); \
          B_.p[1] = __builtin_amdgcn_cvt_pkrtz(R2[0], R3[0]); \
          e0_ = __builtin_amdgcn_mfma_f32_16x16x16f16(dreg##PP, B_.v, z, 0, 0, 0); } \
        { H4U B_; B_.p[0] = __builtin_amdgcn_cvt_pkrtz(R0[1], R1[1]); \
          B_.p[1] = __builtin_amdgcn_cvt_pkrtz(R2[1], R3[1]); \
          e1_ = __builtin_amdgcn_mfma_f32_16x16x16f16(dreg##PP, B_.v, z, 0, 0, 0); } \
        { H4U B_; B_.p[0] = __builtin_amdgcn_cvt_pkrtz(R0[2], R1[2]); \
          B_.p[1] = __builtin_amdgcn_cvt_pkrtz(R2[2], R3[2]); \
          e2_ = __builtin_amdgcn_mfma_f32_16x16x16f16(dreg##PP, B_.v, z, 0, 0, 0); } \
        { H4U B_; B_.p[0] = __builtin_amdgcn_cvt_pkrtz(R0[3], R1[3]); \
          B_.p[1] = __builtin_amdgcn_cvt_pkrtz(R2[3], R3[3]); \
          e3_ = __builtin_amdgcn_mfma_f32_16x16x16f16(dreg##PP, B_.v, z, 0, 0, 0); } \
        P2STORE(PP, e0_, e1_, e2_, e3_) }
        P2F32(0, fA0, fA1, fA2, fA3)
        P2F32(1, fB0, fB1, fB2, fB3)
        fA0 = *(const f32x4*)(fb + (size_t)idC.x*CIN + 4*li);
        fA1 = *(const f32x4*)(fb + (size_t)idC.y*CIN + 4*li);
        fA2 = *(const f32x4*)(fb + (size_t)idC.z*CIN + 4*li);
        fA3 = *(const f32x4*)(fb + (size_t)idC.w*CIN + 4*li);
        fB0 = *(const f32x4*)(fb + (size_t)idD.x*CIN + 4*li);
        fB1 = *(const f32x4*)(fb + (size_t)idD.y*CIN + 4*li);
        fB2 = *(const f32x4*)(fb + (size_t)idD.z*CIN + 4*li);
        fB3 = *(const f32x4*)(fb + (size_t)idD.w*CIN + 4*li);
        P2F32(2, fA0, fA1, fA2, fA3)
        P2F32(3, fB0, fB1, fB2, fB3)
#undef P2F32
    }
#undef P2STORE

    // raw barrier: LDS drained (lgkmcnt) but vmcnt NOT drained (wf in flight)
    asm volatile("s_waitcnt lgkmcnt(0)" ::: "memory");
    __builtin_amdgcn_s_barrier();
    asm volatile("" ::: "memory");

    // ---- phase 3: wave (nq,kkh): partials for BOTH subtiles over its kk-half ----
    __builtin_amdgcn_s_setprio(1);
    f32x4 h0a = {0.f,0.f,0.f,0.f}, h0b = h0a, h1a = h0a, h1b = h0a;
    const unsigned swr = (unsigned)((li & 7) << 4);
#define AR(H, KK) (*(const h8v*)(s_agg + ((H)*16 + li)*2048 + ((((KK))*64 + g*16) ^ swr)))
#define STEP(S, Q, A0, A1) { H8U bu_; bu_.u4 = Q; \
    A0 = __builtin_amdgcn_mfma_f32_16x16x32_f16(AR(0, kkh*16+(S)), bu_.v, A0, 0, 0, 0); \
    A1 = __builtin_amdgcn_mfma_f32_16x16x32_f16(AR(1, kkh*16+(S)), bu_.v, A1, 0, 0, 0); }
#define STEPL(S, Q, A0, A1) STEP(S, Q, A0, A1) Q = wp[(kkh*16+(S)+8)*256];
    STEPL(0, q0, h0a, h1a) STEPL(1, q1, h0b, h1b)
    STEPL(2, q2, h0a, h1a) STEPL(3, q3, h0b, h1b)
    STEPL(4, q4, h0a, h1a) STEPL(5, q5, h0b, h1b)
    STEPL(6, q6, h0a, h1a) STEPL(7, q7, h0b, h1b)
    STEP( 8, q0, h0a, h1a) STEP( 9, q1, h0b, h1b)
    STEP(10, q2, h0a, h1a) STEP(11, q3, h0b, h1b)
    STEP(12, q4, h0a, h1a) STEP(13, q5, h0b, h1b)
    STEP(14, q6, h0a, h1a) STEP(15, q7, h0b, h1b)
#undef STEPL
#undef STEP
#undef AR
    __builtin_amdgcn_s_setprio(0);
    f32x4 acc0 = h0a + h0b;
    f32x4 acc1 = h1a + h1b;

    // ---- pair reduction: (w, w+4) share (nq); partials through dead s_agg ----
    asm volatile("s_waitcnt lgkmcnt(0)" ::: "memory");
    __builtin_amdgcn_s_barrier();          // all s_agg reads complete
    asm volatile("" ::: "memory");
    if (wave >= 4) {
        *(f32x4*)(smem + ((wave-4)*2 + 0)*1024 + l*16) = acc0;
        *(f32x4*)(smem + ((wave-4)*2 + 1)*1024 + l*16) = acc1;
    }
    asm volatile("s_waitcnt lgkmcnt(0)" ::: "memory");
    __builtin_amdgcn_s_barrier();
    asm volatile("" ::: "memory");
    if (wave < 4) {
        const f32x4 p0 = *(const f32x4*)(smem + (wave*2 + 0)*1024 + l*16);
        const f32x4 p1 = *(const f32x4*)(smem + (wave*2 + 1)*1024 + l*16);
        acc0 += p0;
        acc1 += p1;
        #pragma unroll
        for (int r = 0; r < 4; ++r) {
            out[(size_t)(m0 +      g*4 + r)*COUT + nq*16 + li] = acc0[r] + biasO;
            out[(size_t)(m0 + 16 + g*4 + r)*COUT + nq*16 + li] = acc1[r] + biasO;
        }
    }
}

extern "C" void kernel_launch(void* const* d_in, const int* in_sizes, int n_in,
                              void* d_out, int out_size, void* d_ws, size_t ws_size,
                              hipStream_t stream) {
    const float* features   = (const float*)d_in[0];
    const float* input_pts  = (const float*)d_in[1];
    const float* output_pts = (const float*)d_in[2];
    const float* weight     = (const float*)d_in[3];
    const float* bias       = (const float*)d_in[4];
    const float* centers    = (const float*)d_in[5];
    const float* w1         = (const float*)d_in[6];
    const float* b1         = (const float*)d_in[7];
    const float* w2         = (const float*)d_in[8];
    const float* b2         = (const float*)d_in[9];
    const float* w3         = (const float*)d_in[10];
    const float* b3         = (const float*)d_in[11];
    const int*   indices    = (const int*)d_in[12];
    float* out = (float*)d_out;
    unsigned* wsp = (unsigned*)d_ws;
    uint4* wf   = (uint4*)((char*)d_ws + WS_WF_OFF);
    uint4* fb16 = (uint4*)((char*)d_ws + WS_F16_OFF);

    const bool f16ok = ws_size >= WS_NEEDED;
    const int nconv = f16ok ? (4*NPTS*CIN) / (256*8) : 0;
    prep_kernel<<<33 + nconv, 256, 0, stream>>>(
        weight, w1, b1, centers, features, wsp, wf, fb16);

    const int total_pts = 4 * NPTS;   // 65536
    if (f16ok) {
        ptconv_kernel<1><<<total_pts / PTS, 512, 0, stream>>>(
            features, input_pts, output_pts, bias,
            w2, b2, w3, b3, indices, wsp, wf, (const uint2*)fb16, out);
    } else {
        ptconv_kernel<0><<<total_pts / PTS, 512, 0, stream>>>(
            features, input_pts, output_pts, bias,
            w2, b2, w3, b3, indices, wsp, wf, (const uint2*)fb16, out);
    }
}

// Round 15
// 42.110 us; speedup vs baseline: 3.3694x; 1.0120x over previous
//
#include <hip/hip_runtime.h>

#define NPTS 16384
#define KN   16
#define CIN  64
#define COUT 64
#define KSIZ 16
#define PTS  32      // points per block (8 waves)

typedef _Float16 h4v    __attribute__((ext_vector_type(4)));
typedef _Float16 h8v    __attribute__((ext_vector_type(8)));
typedef __fp16   fp16x2 __attribute__((ext_vector_type(2)));
typedef float    f32x4  __attribute__((ext_vector_type(4)));

union H2U { fp16x2 h; unsigned u; };
union H4U { h4v v; fp16x2 p[2]; uint2 u2; };
union H8U { h8v v; uint4 u4; };

#define WS_WF_OFF   512
#define WS_F16_OFF  131584
#define WS_NEEDED   (131584ull + 8388608ull)

// prep: blocks 0..31 pack W*(1/16) into f16 B-fragment order; block 32 folds
// layer-1; blocks 33.. convert features fp32 -> f16 (RNE).
__global__ void prep_kernel(const float* __restrict__ weight,
                            const float* __restrict__ w1,
                            const float* __restrict__ b1,
                            const float* __restrict__ centers,
                            const float* __restrict__ features,
                            unsigned* __restrict__ wsp,
                            uint4* __restrict__ wf,
                            uint4* __restrict__ fb16) {
    const int b = blockIdx.x;
    const int t = threadIdx.x;
    if (b < 32) {
        // slot s (0..1023) <-> (j,c): j = s>>6, c = s&63 (byte 2s in [j][c] f16 row).
        // Fragment: K-step kk, n-tile nt, lane l, elem e -> s = kk*32 + (l>>4)*8 + e,
        // o = nt*16 + (l&15). Consumer uses identical maps -> k-perm-invariant.
        const int bp = b*4 + (t>>6);
        const int kk = bp >> 2, nt = bp & 3;
        const int l = t & 63, li = l & 15, g = l >> 4;
        unsigned short u[8];
        #pragma unroll
        for (int e = 0; e < 8; ++e) {
            int s = kk*32 + g*8 + e;
            int j = s >> 6;
            int c = s & 63;
            union { _Float16 h; unsigned short s16; } cv;
            cv.h = (_Float16)(weight[(c*16 + j)*64 + nt*16 + li] * 0.0625f);
            u[e] = cv.s16;
        }
        uint4 v;
        v.x = u[0] | ((unsigned)u[1] << 16);
        v.y = u[2] | ((unsigned)u[3] << 16);
        v.z = u[4] | ((unsigned)u[5] << 16);
        v.w = u[6] | ((unsigned)u[7] << 16);
        wf[(kk*4 + nt)*64 + l] = v;
    } else if (b == 32) {
        __shared__ float tmp[4][32];
        if (t < 32) {
            int n = t;
            float s0 = 0.f, s1 = 0.f, s2 = 0.f, bf = b1[n];
            for (int s = 0; s < KSIZ; ++s) {
                float a0 = w1[(0*KSIZ + s)*32 + n];
                float a1 = w1[(1*KSIZ + s)*32 + n];
                float a2 = w1[(2*KSIZ + s)*32 + n];
                s0 += a0; s1 += a1; s2 += a2;
                bf -= centers[0*KSIZ+s]*a0 + centers[1*KSIZ+s]*a1 + centers[2*KSIZ+s]*a2;
            }
            tmp[0][n] = s0; tmp[1][n] = s1; tmp[2][n] = s2; tmp[3][n] = bf;
        }
        __syncthreads();
        if (t < 64) {
            const int row = t >> 4, q = t & 15;
            union { _Float16 h[2]; unsigned u; } pk;
            pk.h[0] = (_Float16)tmp[row][2*q];
            pk.h[1] = (_Float16)tmp[row][2*q+1];
            wsp[row*16 + q] = pk.u;
        }
    } else {
        const size_t e0 = ((size_t)(b - 33)*256 + t) * 8;
        const float4 f0 = *(const float4*)(features + e0);
        const float4 f1 = *(const float4*)(features + e0 + 4);
        union { _Float16 h[8]; uint4 v; } o;
        o.h[0] = (_Float16)f0.x; o.h[1] = (_Float16)f0.y;
        o.h[2] = (_Float16)f0.z; o.h[3] = (_Float16)f0.w;
        o.h[4] = (_Float16)f1.x; o.h[5] = (_Float16)f1.y;
        o.h[6] = (_Float16)f1.z; o.h[7] = (_Float16)f1.w;
        fb16[e0 >> 3] = o.v;
    }
}

// FM=1: f16 feature table; FM=0: fp32 features.
// 8 waves: phases 1-2: wave w owns points 4w..4w+3.
// Phase 3: wave w = (nq = w&3, kkh = w>>2); partials for both 16-pt subtiles
// over kk in [kkh*16, kkh*16+16). Pairs (w, w+4) exchange ONE partial each via
// a dedicated LDS region (single barrier), then each group stores its own
// subtile: w<4 -> subtile 0, w>=4 -> subtile 1.
template<int FM>
__global__ __launch_bounds__(512, 4)
void ptconv_kernel(const float* __restrict__ features,
                   const float* __restrict__ input_pts,
                   const float* __restrict__ output_pts,
                   const float* __restrict__ bias,
                   const float* __restrict__ w2,
                   const float* __restrict__ b2,
                   const float* __restrict__ w3,
                   const float* __restrict__ b3,
                   const int*   __restrict__ indices,
                   const unsigned* __restrict__ folded,
                   const uint4* __restrict__ wf,
                   const uint2* __restrict__ fb16,
                   float* __restrict__ out) {
    // LDS 73728 (2 blocks/CU): [0,65536) s_agg[32 pts][2048B] rows [j][c] f16,
    // XOR-swizzled by ((pt&7)<<4) on store and read; wave w's 8KB region doubles
    // as its h1 scratch (l*80B). [65536,73728) pair-reduction scratch (8 slots x 1KB).
    __shared__ __align__(16) char smem[73728];
    char* s_agg = smem;
    char* s_red = smem + 65536;

    const int t    = threadIdx.x;
    const int l    = t & 63;
    const int wave = t >> 6;          // 0..7
    const int li   = l & 15;
    const int g    = l >> 4;
    const int nq   = wave & 3;        // output-column quarter
    const int kkh  = wave >> 2;       // kk-half for phase 3
    const int m0   = blockIdx.x * PTS;
    const int bbk  = m0 >> 14;
    const int mloc = m0 & (NPTS-1);

    const int*   idxB  = indices    + (size_t)bbk*NPTS*KN;
    const float* ptsB  = input_pts  + (size_t)bbk*NPTS*3;
    const float* optsB = output_pts + (size_t)bbk*NPTS*3;
    const float* fb    = features + (size_t)bbk*NPTS*CIN;
    const uint2* fb16B = fb16 + (size_t)bbk*NPTS*(CIN/4);

    // ---- rel chain: per-thread (point p1, neighbor k1); float3 loads ----
    const int p1 = t >> 4, k1 = t & 15;
    const int nn = mloc + p1;
    const int idxv = idxB[nn*KN + k1];
    const float3 opv = *(const float3*)(optsB + nn*3);
    const float3 ipv = *(const float3*)(ptsB + (size_t)idxv*3);

    // ---- neighbor index quads + feature gathers ----
    const int4 idA = *(const int4*)(idxB + (mloc + wave*4+0)*KN + 4*g);
    const int4 idB = *(const int4*)(idxB + (mloc + wave*4+1)*KN + 4*g);
    const int4 idC = *(const int4*)(idxB + (mloc + wave*4+2)*KN + 4*g);
    const int4 idD = *(const int4*)(idxB + (mloc + wave*4+3)*KN + 4*g);

    H4U gA0, gA1, gA2, gA3, gB0, gB1, gB2, gB3;
    H4U gC0, gC1, gC2, gC3, gD0, gD1, gD2, gD3;
    f32x4 fA0, fA1, fA2, fA3, fB0, fB1, fB2, fB3;
    if constexpr (FM == 1) {
        gA0.u2 = fb16B[(size_t)idA.x*16 + li]; gA1.u2 = fb16B[(size_t)idA.y*16 + li];
        gA2.u2 = fb16B[(size_t)idA.z*16 + li]; gA3.u2 = fb16B[(size_t)idA.w*16 + li];
        gB0.u2 = fb16B[(size_t)idB.x*16 + li]; gB1.u2 = fb16B[(size_t)idB.y*16 + li];
        gB2.u2 = fb16B[(size_t)idB.z*16 + li]; gB3.u2 = fb16B[(size_t)idB.w*16 + li];
        gC0.u2 = fb16B[(size_t)idC.x*16 + li]; gC1.u2 = fb16B[(size_t)idC.y*16 + li];
        gC2.u2 = fb16B[(size_t)idC.z*16 + li]; gC3.u2 = fb16B[(size_t)idC.w*16 + li];
        gD0.u2 = fb16B[(size_t)idD.x*16 + li]; gD1.u2 = fb16B[(size_t)idD.y*16 + li];
        gD2.u2 = fb16B[(size_t)idD.z*16 + li]; gD3.u2 = fb16B[(size_t)idD.w*16 + li];
    } else {
        fA0 = *(const f32x4*)(fb + (size_t)idA.x*CIN + 4*li);
        fA1 = *(const f32x4*)(fb + (size_t)idA.y*CIN + 4*li);
        fA2 = *(const f32x4*)(fb + (size_t)idA.z*CIN + 4*li);
        fA3 = *(const f32x4*)(fb + (size_t)idA.w*CIN + 4*li);
        fB0 = *(const f32x4*)(fb + (size_t)idB.x*CIN + 4*li);
        fB1 = *(const f32x4*)(fb + (size_t)idB.y*CIN + 4*li);
        fB2 = *(const f32x4*)(fb + (size_t)idB.z*CIN + 4*li);
        fB3 = *(const f32x4*)(fb + (size_t)idB.w*CIN + 4*li);
    }

    // ---- phase-3 wf preload (independent; issued early for latency slack) ----
    const uint4* wp = wf + nq*64 + l;
    uint4 q0 = wp[(kkh*16+0)*256], q1 = wp[(kkh*16+1)*256];
    uint4 q2 = wp[(kkh*16+2)*256], q3 = wp[(kkh*16+3)*256];
    uint4 q4 = wp[(kkh*16+4)*256], q5 = wp[(kkh*16+5)*256];
    uint4 q6 = wp[(kkh*16+6)*256], q7 = wp[(kkh*16+7)*256];

    // ---- weight fragments / biases ----
    h8v w2f; h4v w3f;
    #pragma unroll
    for (int e = 0; e < 8; ++e) w2f[e] = (_Float16)w2[(8*g+e)*16 + li];
    #pragma unroll
    for (int e = 0; e < 4; ++e) w3f[e] = (_Float16)w3[(4*g+e)*16 + li];
    const f32x4 b2v4  = *(const f32x4*)(b2 + 4*g);
    const float b3v   = b3[li];
    const float biasO = bias[nq*16 + li];

    // ---- layer 1: packed f16 (uniform params -> scalar loads) ----
    {
        const __fp16 r0h = (__fp16)(ipv.x - opv.x);
        const __fp16 r1h = (__fp16)(ipv.y - opv.y);
        const __fp16 r2h = (__fp16)(ipv.z - opv.z);
        fp16x2 r0p = {r0h, r0h}, r1p = {r1h, r1h}, r2p = {r2h, r2h};
        const fp16x2 zz = {(__fp16)0.f, (__fp16)0.f};
        uint4* dst = (uint4*)(smem + wave*8192 + l*80);
        unsigned o8[8];
        #pragma unroll
        for (int half = 0; half < 2; ++half) {
            #pragma unroll
            for (int qq = 0; qq < 8; ++qq) {
                const int q = half*8 + qq;
                H2U a, u0, u1, u2;
                a.u  = folded[48+q];
                u0.u = folded[q];
                u1.u = folded[16+q];
                u2.u = folded[32+q];
                fp16x2 acc = r0p*u0.h + a.h;
                acc = r1p*u1.h + acc;
                acc = r2p*u2.h + acc;
                acc = __builtin_elementwise_max(acc, zz);
                H2U o; o.h = acc; o8[qq] = o.u;
            }
            dst[half*2+0] = make_uint4(o8[0], o8[1], o8[2], o8[3]);
            dst[half*2+1] = make_uint4(o8[4], o8[5], o8[6], o8[7]);
        }
    }

    // ---- layers 2+3 on MFMA, register-chained ----
    h4v dreg0, dreg1, dreg2, dreg3;
#define L23(PP, DREG) { \
    h8v B2 = *(const h8v*)(smem + wave*8192 + ((PP)*16 + li)*80 + g*16); \
    f32x4 a2 = b2v4; \
    a2 = __builtin_amdgcn_mfma_f32_16x16x32_f16(w2f, B2, a2, 0, 0, 0); \
    H4U A3; \
    A3.p[0] = __builtin_amdgcn_cvt_pkrtz(fmaxf(a2[0],0.f), fmaxf(a2[1],0.f)); \
    A3.p[1] = __builtin_amdgcn_cvt_pkrtz(fmaxf(a2[2],0.f), fmaxf(a2[3],0.f)); \
    f32x4 a3 = {b3v, b3v, b3v, b3v}; \
    a3 = __builtin_amdgcn_mfma_f32_16x16x16f16(A3.v, w3f, a3, 0, 0, 0); \
    H4U Dv; \
    Dv.p[0] = __builtin_amdgcn_cvt_pkrtz(fmaxf(a3[0],0.f), fmaxf(a3[1],0.f)); \
    Dv.p[1] = __builtin_amdgcn_cvt_pkrtz(fmaxf(a3[2],0.f), fmaxf(a3[3],0.f)); \
    DREG = Dv.v; }
    L23(0, dreg0) L23(1, dreg1) L23(2, dreg2) L23(3, dreg3)
#undef L23

    // ---- phase 2: agg[j][c] = mfma(dreg, features), K=16; swizzled store ----
#define P2STORE(PP, E0,E1,E2,E3) { \
    const int pix_ = wave*4 + (PP); \
    const unsigned swz_ = (unsigned)((pix_ & 7) << 4); \
    char* ab_ = s_agg + pix_*2048; \
    _Pragma("unroll") \
    for (int r = 0; r < 4; ++r) { \
        H2U d01, d23; \
        d01.h = __builtin_amdgcn_cvt_pkrtz(E0[r], E1[r]); \
        d23.h = __builtin_amdgcn_cvt_pkrtz(E2[r], E3[r]); \
        *(uint2*)(ab_ + ((unsigned)((4*g + r)*128 + 8*li) ^ swz_)) = \
            make_uint2(d01.u, d23.u); \
    } }

    if constexpr (FM == 1) {
#define P2F16(PP, R0,R1,R2,R3) { \
        f32x4 z = {0.f,0.f,0.f,0.f}; \
        f32x4 e0_, e1_, e2_, e3_; \
        { H4U B_; B_.v = (h4v){R0.v[0], R1.v[0], R2.v[0], R3.v[0]}; \
          e0_ = __builtin_amdgcn_mfma_f32_16x16x16f16(dreg##PP, B_.v, z, 0, 0, 0); } \
        { H4U B_; B_.v = (h4v){R0.v[1], R1.v[1], R2.v[1], R3.v[1]}; \
          e1_ = __builtin_amdgcn_mfma_f32_16x16x16f16(dreg##PP, B_.v, z, 0, 0, 0); } \
        { H4U B_; B_.v = (h4v){R0.v[2], R1.v[2], R2.v[2], R3.v[2]}; \
          e2_ = __builtin_amdgcn_mfma_f32_16x16x16f16(dreg##PP, B_.v, z, 0, 0, 0); } \
        { H4U B_; B_.v = (h4v){R0.v[3], R1.v[3], R2.v[3], R3.v[3]}; \
          e3_ = __builtin_amdgcn_mfma_f32_16x16x16f16(dreg##PP, B_.v, z, 0, 0, 0); } \
        P2STORE(PP, e0_, e1_, e2_, e3_) }
        P2F16(0, gA0, gA1, gA2, gA3)
        P2F16(1, gB0, gB1, gB2, gB3)
        P2F16(2, gC0, gC1, gC2, gC3)
        P2F16(3, gD0, gD1, gD2, gD3)
#undef P2F16
    } else {
#define P2F32(PP, R0,R1,R2,R3) { \
        f32x4 z = {0.f,0.f,0.f,0.f}; \
        f32x4 e0_, e1_, e2_, e3_; \
        { H4U B_; B_.p[0] = __builtin_amdgcn_cvt_pkrtz(R0[0], R1[0]); \
          B_.p[1] = __builtin_amdgcn_cvt_pkrtz(R2[0], R3[0]); \
          e0_ = __builtin_amdgcn_mfma_f32_16x16x16f16(dreg##PP, B_.v, z, 0, 0, 0); } \
        { H4U B_; B_.p[0] = __builtin_amdgcn_cvt_pkrtz(R0[1], R1[1]); \
          B_.p[1] = __builtin_amdgcn_cvt_pkrtz(R2[1], R3[1]); \
          e1_ = __builtin_amdgcn_mfma_f32_16x16x16f16(dreg##PP, B_.v, z, 0, 0, 0); } \
        { H4U B_; B_.p[0] = __builtin_amdgcn_cvt_pkrtz(R0[2], R1[2]); \
          B_.p[1] = __builtin_amdgcn_cvt_pkrtz(R2[2], R3[2]); \
          e2_ = __builtin_amdgcn_mfma_f32_16x16x16f16(dreg##PP, B_.v, z, 0, 0, 0); } \
        { H4U B_; B_.p[0] = __builtin_amdgcn_cvt_pkrtz(R0[3], R1[3]); \
          B_.p[1] = __builtin_amdgcn_cvt_pkrtz(R2[3], R3[3]); \
          e3_ = __builtin_amdgcn_mfma_f32_16x16x16f16(dreg##PP, B_.v, z, 0, 0, 0); } \
        P2STORE(PP, e0_, e1_, e2_, e3_) }
        P2F32(0, fA0, fA1, fA2, fA3)
        P2F32(1, fB0, fB1, fB2, fB3)
        fA0 = *(const f32x4*)(fb + (size_t)idC.x*CIN + 4*li);
        fA1 = *(const f32x4*)(fb + (size_t)idC.y*CIN + 4*li);
        fA2 = *(const f32x4*)(fb + (size_t)idC.z*CIN + 4*li);
        fA3 = *(const f32x4*)(fb + (size_t)idC.w*CIN + 4*li);
        fB0 = *(const f32x4*)(fb + (size_t)idD.x*CIN + 4*li);
        fB1 = *(const f32x4*)(fb + (size_t)idD.y*CIN + 4*li);
        fB2 = *(const f32x4*)(fb + (size_t)idD.z*CIN + 4*li);
        fB3 = *(const f32x4*)(fb + (size_t)idD.w*CIN + 4*li);
        P2F32(2, fA0, fA1, fA2, fA3)
        P2F32(3, fB0, fB1, fB2, fB3)
#undef P2F32
    }
#undef P2STORE

    // raw barrier: LDS drained (lgkmcnt) but vmcnt NOT drained (wf in flight)
    asm volatile("s_waitcnt lgkmcnt(0)" ::: "memory");
    __builtin_amdgcn_s_barrier();
    asm volatile("" ::: "memory");

    // ---- phase 3: wave (nq,kkh): partials for BOTH subtiles over its kk-half ----
    __builtin_amdgcn_s_setprio(1);
    f32x4 h0a = {0.f,0.f,0.f,0.f}, h0b = h0a, h1a = h0a, h1b = h0a;
    const unsigned swr = (unsigned)((li & 7) << 4);
#define AR(H, KK) (*(const h8v*)(s_agg + ((H)*16 + li)*2048 + ((((KK))*64 + g*16) ^ swr)))
#define STEP(S, Q, A0, A1) { H8U bu_; bu_.u4 = Q; \
    A0 = __builtin_amdgcn_mfma_f32_16x16x32_f16(AR(0, kkh*16+(S)), bu_.v, A0, 0, 0, 0); \
    A1 = __builtin_amdgcn_mfma_f32_16x16x32_f16(AR(1, kkh*16+(S)), bu_.v, A1, 0, 0, 0); }
#define STEPL(S, Q, A0, A1) STEP(S, Q, A0, A1) Q = wp[(kkh*16+(S)+8)*256];
    STEPL(0, q0, h0a, h1a) STEPL(1, q1, h0b, h1b)
    STEPL(2, q2, h0a, h1a) STEPL(3, q3, h0b, h1b)
    STEPL(4, q4, h0a, h1a) STEPL(5, q5, h0b, h1b)
    STEPL(6, q6, h0a, h1a) STEPL(7, q7, h0b, h1b)
    STEP( 8, q0, h0a, h1a) STEP( 9, q1, h0b, h1b)
    STEP(10, q2, h0a, h1a) STEP(11, q3, h0b, h1b)
    STEP(12, q4, h0a, h1a) STEP(13, q5, h0b, h1b)
    STEP(14, q6, h0a, h1a) STEP(15, q7, h0b, h1b)
#undef STEPL
#undef STEP
#undef AR
    __builtin_amdgcn_s_setprio(0);
    f32x4 acc0 = h0a + h0b;
    f32x4 acc1 = h1a + h1b;

    // ---- symmetric pair exchange through dedicated s_red (ONE barrier) ----
    // w>=4 ships subtile-0 partial; w<4 ships subtile-1 partial.
    if (wave >= 4) *(f32x4*)(s_red + (nq*2 + 0)*1024 + l*16) = acc0;
    else           *(f32x4*)(s_red + (nq*2 + 1)*1024 + l*16) = acc1;
    asm volatile("s_waitcnt lgkmcnt(0)" ::: "memory");
    __builtin_amdgcn_s_barrier();
    asm volatile("" ::: "memory");
    if (wave < 4) {
        acc0 += *(const f32x4*)(s_red + (nq*2 + 0)*1024 + l*16);
        #pragma unroll
        for (int r = 0; r < 4; ++r)
            out[(size_t)(m0 + g*4 + r)*COUT + nq*16 + li] = acc0[r] + biasO;
    } else {
        acc1 += *(const f32x4*)(s_red + (nq*2 + 1)*1024 + l*16);
        #pragma unroll
        for (int r = 0; r < 4; ++r)
            out[(size_t)(m0 + 16 + g*4 + r)*COUT + nq*16 + li] = acc1[r] + biasO;
    }
}

extern "C" void kernel_launch(void* const* d_in, const int* in_sizes, int n_in,
                              void* d_out, int out_size, void* d_ws, size_t ws_size,
                              hipStream_t stream) {
    const float* features   = (const float*)d_in[0];
    const float* input_pts  = (const float*)d_in[1];
    const float* output_pts = (const float*)d_in[2];
    const float* weight     = (const float*)d_in[3];
    const float* bias       = (const float*)d_in[4];
    const float* centers    = (const float*)d_in[5];
    const float* w1         = (const float*)d_in[6];
    const float* b1         = (const float*)d_in[7];
    const float* w2         = (const float*)d_in[8];
    const float* b2         = (const float*)d_in[9];
    const float* w3         = (const float*)d_in[10];
    const float* b3         = (const float*)d_in[11];
    const int*   indices    = (const int*)d_in[12];
    float* out = (float*)d_out;
    unsigned* wsp = (unsigned*)d_ws;
    uint4* wf   = (uint4*)((char*)d_ws + WS_WF_OFF);
    uint4* fb16 = (uint4*)((char*)d_ws + WS_F16_OFF);

    const bool f16ok = ws_size >= WS_NEEDED;
    const int nconv = f16ok ? (4*NPTS*CIN) / (256*8) : 0;
    prep_kernel<<<33 + nconv, 256, 0, stream>>>(
        weight, w1, b1, centers, features, wsp, wf, fb16);

    const int total_pts = 4 * NPTS;   // 65536
    if (f16ok) {
        ptconv_kernel<1><<<total_pts / PTS, 512, 0, stream>>>(
            features, input_pts, output_pts, bias,
            w2, b2, w3, b3, indices, wsp, wf, (const uint2*)fb16, out);
    } else {
        ptconv_kernel<0><<<total_pts / PTS, 512, 0, stream>>>(
            features, input_pts, output_pts, bias,
            w2, b2, w3, b3, indices, wsp, wf, (const uint2*)fb16, out);
    }
}